// Round 3
// baseline (2175.017 us; speedup 1.0000x reference)
//
#include <hip/hip_runtime.h>
#include <math.h>

#define BB 4
#define TT 1024
#define CC 48
#define HH 8
#define THD_B (HH*TT)     // 8192 token-heads per batch
#define FF 544            // padded feature dim (528 bilinear + qn/kn + pad)
#define CK (CC*16)        // 768
#define HCK (HH*CK)       // 6144

// per-component tables: grade slice, e0 slice, e0 source comp, feature index
// e0 maps move s->d: 0->1, 2->5, 3->6, 4->7, 8->11, 9->12, 10->13, 14->15
// so DESTINATIONS {1,5,6,7,11,12,13,15} carry the e-term from their source comp.
__constant__ int c_gj[16]   = {0,1,1,1,1,2,2,2,2,2,2,3,3,3,3,4};
__constant__ int c_ej[16]   = {-1,5,-1,-1,-1,6,6,6,-1,-1,-1,7,7,7,-1,8};
__constant__ int c_srcj[16] = {0,0,0,0,0,2,3,4,0,0,0,8,9,10,0,14};
__constant__ int c_fi[16]   = {0,-1,1,2,3,-1,-1,-1,4,5,6,8,9,10,7,-1};

// ---------------- sentinel fill (workspace too small diagnostic) ----------------
__global__ void kfill(float* __restrict__ p, size_t n, float v) {
  size_t i = (size_t)blockIdx.x*256 + threadIdx.x;
  size_t stride = (size_t)gridDim.x*256;
  for (; i < n; i += stride) p[i] = v;
}

// ---------------- K0: transpose weights to slice-major ----------------
__global__ void k0_transpose_w(const float* __restrict__ w_attn,
                               const float* __restrict__ w_next,
                               float* __restrict__ wTa, float* __restrict__ wTn) {
  int idx = blockIdx.x*256 + threadIdx.x;
  if (idx < 1152*48) {
    int o = idx / 48, i = idx % 48;
    #pragma unroll
    for (int a = 0; a < 9; ++a)
      wTa[((size_t)a*1152 + o)*48 + i] = w_attn[((size_t)o*48 + i)*9 + a];
  }
  if (idx < 48*384) {
    int o = idx / 384, i = idx % 384;
    #pragma unroll
    for (int a = 0; a < 9; ++a)
      wTn[((size_t)a*48 + o)*384 + i] = w_next[((size_t)o*384 + i)*9 + a];
  }
}

// ---------------- K1: equi RMS norm -> hT[comp][token][chan]  (per batch b) ----------------
__global__ __launch_bounds__(256) void k1_rmsnorm(const float* __restrict__ hidden_b,
                                                  const float* __restrict__ lnw,
                                                  float* __restrict__ hT) {
  int n = blockIdx.x, tid = threadIdx.x;
  __shared__ float xs[768];
  __shared__ float red[256];
  float psum = 0.f;
  for (int e = tid; e < 768; e += 256) {
    float v = hidden_b[(size_t)n*768 + e];
    xs[e] = v;
    int k = e & 15;
    if ((0x471Du >> k) & 1u) psum += v*v;   // INV = {0,2,3,4,8,9,10,14}
  }
  red[tid] = psum;
  __syncthreads();
  for (int s = 128; s > 0; s >>= 1) { if (tid < s) red[tid] += red[tid+s]; __syncthreads(); }
  float scale = rsqrtf(red[0]/48.0f + 1e-6f);
  for (int e = tid; e < 768; e += 256) {
    int k = e / 48, i = e % 48;
    hT[((size_t)k*TT + n)*48 + i] = xs[i*16 + k] * scale * lnw[i];
  }
}

// ---------------- K1b: qkv equi-linear as per-component GEMMs (per batch b) ----------------
// grid (ntile=16, otile=18, j=16). out[t, o] for plane j.
__global__ __launch_bounds__(256) void k1b_qkv(const float* __restrict__ hT,
                                               const float* __restrict__ wTa,
                                               const float* __restrict__ b_attn,
                                               float* __restrict__ qf,
                                               float* __restrict__ kf,
                                               float* __restrict__ vbuf) {
  const int j  = blockIdx.z;
  const int fi = c_fi[j];
  const int oy = blockIdx.y;
  if (fi < 0 && oy < 12) return;        // q/k never use comps {1,5,6,7,15}
  const int nx = blockIdx.x;
  const int g = c_gj[j], e = c_ej[j], srcc = c_srcj[j];
  const int nk = (e >= 0) ? 2 : 1;
  const int KDIM = 48*nk;
  __shared__ float As[64][100];
  __shared__ float Bs[64][100];
  const int tid = threadIdx.x;
  {
    const int n0 = nx*64;
    for (int p = 0; p < nk; ++p) {
      int jp = (p == 0) ? j : srcc;
      const float* sa = hT + ((size_t)jp*TT + n0)*48;
      int a = (p == 0) ? g : e;
      const float* sb = wTa + ((size_t)a*1152 + oy*64)*48;
      for (int idx = tid; idx < 64*12; idx += 256) {
        int r = idx / 12, i4 = (idx % 12)*4;
        *(float4*)(&As[r][p*48 + i4]) = *(const float4*)(sa + (size_t)r*48 + i4);
        *(float4*)(&Bs[r][p*48 + i4]) = *(const float4*)(sb + (size_t)r*48 + i4);
      }
    }
  }
  __syncthreads();
  const int tx = tid % 16, ty = tid / 16;
  float acc[4][4] = {};
  for (int k4 = 0; k4 < KDIM; k4 += 4) {
    float4 a4[4], b4[4];
    #pragma unroll
    for (int m = 0; m < 4; ++m) a4[m] = *(const float4*)(&As[ty*4+m][k4]);
    #pragma unroll
    for (int m = 0; m < 4; ++m) b4[m] = *(const float4*)(&Bs[tx*4+m][k4]);
    #pragma unroll
    for (int r = 0; r < 4; ++r)
      #pragma unroll
      for (int c = 0; c < 4; ++c)
        acc[r][c] += a4[r].x*b4[c].x + a4[r].y*b4[c].y + a4[r].z*b4[c].z + a4[r].w*b4[c].w;
  }
  const float scl = (j >= 11 && j <= 13) ? 1.41421356237f : 1.0f;
  const int o0 = oy*64 + tx*4;
  const int qkv = o0 / 384, rem = o0 % 384, head = rem / 48, c = rem % 48;
  const int n0 = nx*64 + ty*4;
  #pragma unroll
  for (int r = 0; r < 4; ++r) {
    int t = n0 + r;
    size_t th = (size_t)head*TT + t;
    float4 v = make_float4(acc[r][0], acc[r][1], acc[r][2], acc[r][3]);
    if (j == 0) { v.x += b_attn[o0]; v.y += b_attn[o0+1]; v.z += b_attn[o0+2]; v.w += b_attn[o0+3]; }
    if (qkv == 2) {
      *(float4*)(vbuf + th*CK + j*48 + c) = v;
    } else {
      v.x *= scl; v.y *= scl; v.z *= scl; v.w *= scl;
      float* dst = (qkv == 0 ? qf : kf) + th*FF + fi*48 + c;
      *(float4*)dst = v;
    }
  }
}

// ---------------- K1c: append qn/kn rank-1 features + zero padding (per b) ----------------
__global__ void k1c_extras(float* __restrict__ qf, float* __restrict__ kf) {
  int th = blockIdx.x*256 + threadIdx.x;
  if (th >= THD_B) return;
  float* q = qf + (size_t)th*FF;
  float* k = kf + (size_t)th*FF;
  float qn = 0.f, kn = 0.f;
  for (int e = 8*48; e < 11*48; ++e) { qn += q[e]*q[e]; kn += k[e]*k[e]; }
  qn *= 0.5f; kn *= 0.5f;              // features hold sqrt(2)*proj
  q[528] = qn;   q[529] = 1.f;
  k[528] = -1.f; k[529] = -kn;
  #pragma unroll
  for (int e = 530; e < FF; ++e) { q[e] = 0.f; k[e] = 0.f; }
}

// ---------------- K2b: logits = (qf . kf) / sqrt(384)  (head chunk) ----------------
// grid (stile=16, ttile=16, lh=hg)
__global__ __launch_bounds__(256) void k2b_logits(const float* __restrict__ qf,
                                                  const float* __restrict__ kf,
                                                  float* __restrict__ logits,
                                                  int hh0) {
  const int lh = blockIdx.z;
  const int h  = hh0 + lh;
  const int t0 = blockIdx.y * 64;
  const int s0 = blockIdx.x * 64;
  const float* A  = qf + (size_t)h*TT*FF;
  const float* Bm = kf + (size_t)h*TT*FF;
  __shared__ float As[64][36];
  __shared__ float Bs[64][36];
  const int tid = threadIdx.x;
  const int tx = tid % 16, ty = tid / 16;
  float acc[4][4] = {};
  for (int kk = 0; kk < FF; kk += 32) {
    __syncthreads();
    for (int idx = tid; idx < 512; idx += 256) {
      int r = idx / 8, c4 = (idx % 8)*4;
      *(float4*)(&As[r][c4]) = *(const float4*)(A  + (size_t)(t0 + r)*FF + kk + c4);
      *(float4*)(&Bs[r][c4]) = *(const float4*)(Bm + (size_t)(s0 + r)*FF + kk + c4);
    }
    __syncthreads();
    #pragma unroll
    for (int k4 = 0; k4 < 32; k4 += 4) {
      float4 a4[4], b4[4];
      #pragma unroll
      for (int m = 0; m < 4; ++m) a4[m] = *(const float4*)(&As[ty*4+m][k4]);
      #pragma unroll
      for (int m = 0; m < 4; ++m) b4[m] = *(const float4*)(&Bs[tx*4+m][k4]);
      #pragma unroll
      for (int r = 0; r < 4; ++r)
        #pragma unroll
        for (int c = 0; c < 4; ++c)
          acc[r][c] += a4[r].x*b4[c].x + a4[r].y*b4[c].y + a4[r].z*b4[c].z + a4[r].w*b4[c].w;
    }
  }
  const float iscl = 0.051031036307982884f;   // 1/sqrt(384)
  #pragma unroll
  for (int r = 0; r < 4; ++r) {
    float4 v = make_float4(acc[r][0]*iscl, acc[r][1]*iscl, acc[r][2]*iscl, acc[r][3]*iscl);
    *(float4*)(logits + ((size_t)lh*TT + t0 + ty*4 + r)*TT + s0 + tx*4) = v;
  }
}

// ---------------- K2c: row softmax in-place ----------------
__global__ __launch_bounds__(256) void k2c_softmax(float* __restrict__ logits) {
  int row = blockIdx.x * 4 + (threadIdx.x >> 6);
  int lane = threadIdx.x & 63;
  float* p = logits + (size_t)row * TT;
  float4 v[4];
  float mx = -1e30f;
  #pragma unroll
  for (int m = 0; m < 4; ++m) {
    v[m] = *(const float4*)(p + (m*64 + lane)*4);
    mx = fmaxf(mx, fmaxf(fmaxf(v[m].x, v[m].y), fmaxf(v[m].z, v[m].w)));
  }
  #pragma unroll
  for (int off = 32; off; off >>= 1) mx = fmaxf(mx, __shfl_xor(mx, off, 64));
  float sum = 0.f;
  #pragma unroll
  for (int m = 0; m < 4; ++m) {
    v[m].x = __expf(v[m].x - mx); v[m].y = __expf(v[m].y - mx);
    v[m].z = __expf(v[m].z - mx); v[m].w = __expf(v[m].w - mx);
    sum += v[m].x + v[m].y + v[m].z + v[m].w;
  }
  #pragma unroll
  for (int off = 32; off; off >>= 1) sum += __shfl_xor(sum, off, 64);
  float inv = 1.0f / sum;
  #pragma unroll
  for (int m = 0; m < 4; ++m) {
    v[m].x *= inv; v[m].y *= inv; v[m].z *= inv; v[m].w *= inv;
    *(float4*)(p + (m*64 + lane)*4) = v[m];
  }
}

// ---------------- K2d: ao[t][h*768 + j*48 + c] = probs @ V  (head chunk) ----------------
// grid (ctile=12, ttile=16, lh=hg)
__global__ __launch_bounds__(256) void k2d_pv(const float* __restrict__ probs,
                                              const float* __restrict__ vbuf,
                                              float* __restrict__ ao,
                                              int hh0) {
  const int lh = blockIdx.z;
  const int h  = hh0 + lh;
  const int t0 = blockIdx.y * 64;
  const int c0 = blockIdx.x * 64;
  const float* A  = probs + (size_t)lh*TT*TT;
  const float* Bm = vbuf  + (size_t)h*TT*CK;
  __shared__ float As[64][36];
  __shared__ float Bs[32][68];
  const int tid = threadIdx.x;
  const int tx = tid % 16, ty = tid / 16;
  float acc[4][4] = {};
  for (int kk = 0; kk < TT; kk += 32) {
    __syncthreads();
    for (int idx = tid; idx < 512; idx += 256) {
      int r = idx / 8, c4 = (idx % 8)*4;
      *(float4*)(&As[r][c4]) = *(const float4*)(A + (size_t)(t0 + r)*TT + kk + c4);
    }
    for (int idx = tid; idx < 512; idx += 256) {
      int s = idx / 16, c4 = (idx % 16)*4;
      *(float4*)(&Bs[s][c4]) = *(const float4*)(Bm + (size_t)(kk + s)*CK + c0 + c4);
    }
    __syncthreads();
    #pragma unroll
    for (int k4 = 0; k4 < 32; k4 += 4) {
      float4 a4[4];
      #pragma unroll
      for (int m = 0; m < 4; ++m) a4[m] = *(const float4*)(&As[ty*4+m][k4]);
      #pragma unroll
      for (int k2 = 0; k2 < 4; ++k2) {
        float4 b4 = *(const float4*)(&Bs[k4+k2][tx*4]);
        #pragma unroll
        for (int r = 0; r < 4; ++r) {
          float av = (k2 == 0) ? a4[r].x : (k2 == 1) ? a4[r].y : (k2 == 2) ? a4[r].z : a4[r].w;
          acc[r][0] += av*b4.x; acc[r][1] += av*b4.y; acc[r][2] += av*b4.z; acc[r][3] += av*b4.w;
        }
      }
    }
  }
  #pragma unroll
  for (int r = 0; r < 4; ++r) {
    int t = t0 + ty*4 + r;
    float4 v = make_float4(acc[r][0], acc[r][1], acc[r][2], acc[r][3]);
    *(float4*)(ao + (size_t)t*HCK + h*CK + c0 + tx*4) = v;
  }
}

// ---------------- K3: out-projection equi-linear + bias + residual (per b) ----------------
__global__ __launch_bounds__(256) void k3_final(const float* __restrict__ ao,
                                                const float* __restrict__ wTn,
                                                const float* __restrict__ b_next,
                                                const float* __restrict__ hidden_b,
                                                float* __restrict__ out_b) {
  const int n0 = blockIdx.x * 2;
  const int tid = threadIdx.x;
  __shared__ float aos[2][8*16*52];
  #pragma unroll
  for (int tt = 0; tt < 2; ++tt) {
    const float* src = ao + (size_t)(n0 + tt)*HCK;
    for (int idx = tid; idx < HCK/4; idx += 256) {
      int m4 = idx*4;
      int h = m4 / CK, r = m4 % CK;
      *(float4*)(&aos[tt][(h*16 + (r/48))*52 + (r%48)]) = *(const float4*)(src + m4);
    }
  }
  __syncthreads();
  const int j = tid & 15;
  const int og = tid >> 4;
  const int g = c_gj[j], e = c_ej[j], srcc = c_srcj[j];
  float accA[3] = {0.f,0.f,0.f}, accB[3] = {0.f,0.f,0.f};
  for (int h = 0; h < HH; ++h) {
    const int xbase = (h*16 + j)*52;
    const int sbase = (h*16 + srcc)*52;
    for (int c4 = 0; c4 < 48; c4 += 4) {
      float4 x0 = *(const float4*)(&aos[0][xbase + c4]);
      float4 x1 = *(const float4*)(&aos[1][xbase + c4]);
      #pragma unroll
      for (int m = 0; m < 3; ++m) {
        int o = og + m*16;
        float4 w = *(const float4*)(wTn + ((size_t)g*48 + o)*384 + h*48 + c4);
        accA[m] += w.x*x0.x + w.y*x0.y + w.z*x0.z + w.w*x0.w;
        accB[m] += w.x*x1.x + w.y*x1.y + w.z*x1.z + w.w*x1.w;
      }
      if (e >= 0) {
        float4 s0 = *(const float4*)(&aos[0][sbase + c4]);
        float4 s1 = *(const float4*)(&aos[1][sbase + c4]);
        #pragma unroll
        for (int m = 0; m < 3; ++m) {
          int o = og + m*16;
          float4 w = *(const float4*)(wTn + ((size_t)e*48 + o)*384 + h*48 + c4);
          accA[m] += w.x*s0.x + w.y*s0.y + w.z*s0.z + w.w*s0.w;
          accB[m] += w.x*s1.x + w.y*s1.y + w.z*s1.z + w.w*s1.w;
        }
      }
    }
  }
  #pragma unroll
  for (int m = 0; m < 3; ++m) {
    int o = og + m*16;
    float bb = (j == 0) ? b_next[o] : 0.f;
    size_t offA = (size_t)n0*768 + o*16 + j;
    size_t offB = (size_t)(n0+1)*768 + o*16 + j;
    out_b[offA] = accA[m] + bb + hidden_b[offA];
    out_b[offB] = accB[m] + bb + hidden_b[offB];
  }
}

extern "C" void kernel_launch(void* const* d_in, const int* in_sizes, int n_in,
                              void* d_out, int out_size, void* d_ws, size_t ws_size,
                              hipStream_t stream) {
  const float* hidden = (const float*)d_in[0];
  const float* w_attn = (const float*)d_in[1];
  const float* b_attn = (const float*)d_in[2];
  const float* w_next = (const float*)d_in[3];
  const float* b_next = (const float*)d_in[4];
  const float* ln_w   = (const float*)d_in[5];
  float* out = (float*)d_out;
  float* ws = (float*)d_ws;

  // fixed (per-b reused) buffers in floats: qf+kf (2*8192*544) + vbuf+ao (2*6291456) + wTa + wTn
  const size_t FIXED_FL = 2ull*THD_B*FF + 2ull*6291456 + 497664 + 165888;  // 22,159,360
  int hg = 0;
  if      (ws_size >= (8ull*1048576 + FIXED_FL)*4) hg = 8;
  else if (ws_size >= (4ull*1048576 + FIXED_FL)*4) hg = 4;
  else if (ws_size >= (2ull*1048576 + FIXED_FL)*4) hg = 2;
  else if (ws_size >= (1ull*1048576 + FIXED_FL)*4) hg = 1;
  if (hg == 0) {
    // workspace too small even for hg=1 (88.5 MiB): emit sentinel so the
    // failure is distinguishable (error ~1e6 => ws_size is the problem)
    kfill<<<2048, 256, 0, stream>>>(out, (size_t)out_size, 1.0e6f);
    return;
  }

  float* logits = ws;                          // hg * 1M floats (also aliases hT: disjoint lifetime)
  float* hT     = ws;                          // 786,432 floats, dead before logits written
  float* qf     = ws + (size_t)hg*1048576;     // 4,456,448
  float* kf     = qf + (size_t)THD_B*FF;       // 4,456,448
  float* vbuf   = kf + (size_t)THD_B*FF;       // 6,291,456
  float* ao     = vbuf + 6291456;              // 6,291,456
  float* wTa    = ao + 6291456;                // 497,664
  float* wTn    = wTa + 497664;                // 165,888

  k0_transpose_w<<<216, 256, 0, stream>>>(w_attn, w_next, wTa, wTn);
  for (int b = 0; b < BB; ++b) {
    const float* hid_b = hidden + (size_t)b*TT*768;
    float* out_b = out + (size_t)b*TT*768;
    k1_rmsnorm<<<TT, 256, 0, stream>>>(hid_b, ln_w, hT);
    k1b_qkv<<<dim3(16, 18, 16), 256, 0, stream>>>(hT, wTa, b_attn, qf, kf, vbuf);
    k1c_extras<<<THD_B/256, 256, 0, stream>>>(qf, kf);
    for (int hh0 = 0; hh0 < HH; hh0 += hg) {
      k2b_logits<<<dim3(16, 16, hg), 256, 0, stream>>>(qf, kf, logits, hh0);
      k2c_softmax<<<hg*256, 256, 0, stream>>>(logits);
      k2d_pv<<<dim3(12, 16, hg), 256, 0, stream>>>(logits, vbuf, ao, hh0);
    }
    k3_final<<<TT/2, 256, 0, stream>>>(ao, wTn, b_next, hid_b, out_b);
  }
}

// Round 4
// 853.012 us; speedup vs baseline: 2.5498x; 2.5498x over previous
//
#include <hip/hip_runtime.h>
#include <math.h>

#define BB 4
#define TT 1024
#define CC 48
#define HH 8
#define THD_B (HH*TT)     // 8192 token-heads per batch
#define FF 544            // padded feature dim (528 bilinear + qn/kn + pad), 17*32
#define CK (CC*16)        // 768
#define HCK (HH*CK)       // 6144

typedef __attribute__((ext_vector_type(8))) short bf16x8;
typedef __attribute__((ext_vector_type(4))) float f32x4;

// per-component tables: grade slice, e0 slice, e0 source comp, feature index
// e0 maps move s->d: 0->1, 2->5, 3->6, 4->7, 8->11, 9->12, 10->13, 14->15
__constant__ int c_gj[16]   = {0,1,1,1,1,2,2,2,2,2,2,3,3,3,3,4};
__constant__ int c_ej[16]   = {-1,5,-1,-1,-1,6,6,6,-1,-1,-1,7,7,7,-1,8};
__constant__ int c_srcj[16] = {0,0,0,0,0,2,3,4,0,0,0,8,9,10,0,14};
__constant__ int c_fi[16]   = {0,-1,1,2,3,-1,-1,-1,4,5,6,8,9,10,7,-1};

__device__ inline ushort f2bf(float x) {           // RNE float->bf16
  union { float f; unsigned u; } a; a.f = x;
  unsigned r = a.u + 0x7FFFu + ((a.u >> 16) & 1u);
  return (ushort)(r >> 16);
}
__device__ inline float bf2f(ushort u) {
  union { unsigned u; float f; } a; a.u = ((unsigned)u) << 16; return a.f;
}
// LDS tile [rows][32 ushorts]; 16B-block XOR swizzle: blk' = blk ^ ((row>>2)&3)
// -> 16-lane stride-64B fragment reads land 2-way per bank (free, m136)
__device__ inline int swzi(int row, int blk) {
  return row*32 + (((blk ^ (row >> 2)) & 3) << 3);
}

// ---------------- sentinel fill (workspace too small diagnostic) ----------------
__global__ void kfill(float* __restrict__ p, size_t n, float v) {
  size_t i = (size_t)blockIdx.x*256 + threadIdx.x;
  size_t stride = (size_t)gridDim.x*256;
  for (; i < n; i += stride) p[i] = v;
}

// ---------------- K0: transpose weights to slice-major ----------------
__global__ void k0_transpose_w(const float* __restrict__ w_attn,
                               const float* __restrict__ w_next,
                               float* __restrict__ wTa, float* __restrict__ wTn) {
  int idx = blockIdx.x*256 + threadIdx.x;
  if (idx < 1152*48) {
    int o = idx / 48, i = idx % 48;
    #pragma unroll
    for (int a = 0; a < 9; ++a)
      wTa[((size_t)a*1152 + o)*48 + i] = w_attn[((size_t)o*48 + i)*9 + a];
  }
  if (idx < 48*384) {
    int o = idx / 384, i = idx % 384;
    #pragma unroll
    for (int a = 0; a < 9; ++a)
      wTn[((size_t)a*48 + o)*384 + i] = w_next[((size_t)o*384 + i)*9 + a];
  }
}

// ---------------- K1: equi RMS norm -> hT[comp][token][chan]  (per batch) ----------------
__global__ __launch_bounds__(256) void k1_rmsnorm(const float* __restrict__ hidden_b,
                                                  const float* __restrict__ lnw,
                                                  float* __restrict__ hT) {
  int n = blockIdx.x, tid = threadIdx.x;
  __shared__ float xs[768];
  __shared__ float red[256];
  float psum = 0.f;
  for (int e = tid; e < 768; e += 256) {
    float v = hidden_b[(size_t)n*768 + e];
    xs[e] = v;
    int k = e & 15;
    if ((0x471Du >> k) & 1u) psum += v*v;   // INV = {0,2,3,4,8,9,10,14}
  }
  red[tid] = psum;
  __syncthreads();
  for (int s = 128; s > 0; s >>= 1) { if (tid < s) red[tid] += red[tid+s]; __syncthreads(); }
  float scale = rsqrtf(red[0]/48.0f + 1e-6f);
  for (int e = tid; e < 768; e += 256) {
    int k = e / 48, i = e % 48;
    hT[((size_t)k*TT + n)*48 + i] = xs[i*16 + k] * scale * lnw[i];
  }
}

// ---------------- K1b: qkv equi-linear, fp32 microtile, bf16 outputs ----------------
__global__ __launch_bounds__(256) void k1b_qkv(const float* __restrict__ hT,
                                               const float* __restrict__ wTa,
                                               const float* __restrict__ b_attn,
                                               ushort* __restrict__ qf,
                                               ushort* __restrict__ kf,
                                               ushort* __restrict__ vb) {
  const int j  = blockIdx.z;
  const int fi = c_fi[j];
  const int oy = blockIdx.y;
  if (fi < 0 && oy < 12) return;        // q/k never use comps {1,5,6,7,15}
  const int nx = blockIdx.x;
  const int g = c_gj[j], e = c_ej[j], srcc = c_srcj[j];
  const int nk = (e >= 0) ? 2 : 1;
  const int KDIM = 48*nk;
  __shared__ float As[64][100];
  __shared__ float Bs[64][100];
  const int tid = threadIdx.x;
  {
    const int n0 = nx*64;
    for (int p = 0; p < nk; ++p) {
      int jp = (p == 0) ? j : srcc;
      const float* sa = hT + ((size_t)jp*TT + n0)*48;
      int a = (p == 0) ? g : e;
      const float* sb = wTa + ((size_t)a*1152 + oy*64)*48;
      for (int idx = tid; idx < 64*12; idx += 256) {
        int r = idx / 12, i4 = (idx % 12)*4;
        *(float4*)(&As[r][p*48 + i4]) = *(const float4*)(sa + (size_t)r*48 + i4);
        *(float4*)(&Bs[r][p*48 + i4]) = *(const float4*)(sb + (size_t)r*48 + i4);
      }
    }
  }
  __syncthreads();
  const int tx = tid % 16, ty = tid / 16;
  float acc[4][4] = {};
  for (int k4 = 0; k4 < KDIM; k4 += 4) {
    float4 a4[4], b4[4];
    #pragma unroll
    for (int m = 0; m < 4; ++m) a4[m] = *(const float4*)(&As[ty*4+m][k4]);
    #pragma unroll
    for (int m = 0; m < 4; ++m) b4[m] = *(const float4*)(&Bs[tx*4+m][k4]);
    #pragma unroll
    for (int r = 0; r < 4; ++r)
      #pragma unroll
      for (int c = 0; c < 4; ++c)
        acc[r][c] += a4[r].x*b4[c].x + a4[r].y*b4[c].y + a4[r].z*b4[c].z + a4[r].w*b4[c].w;
  }
  const float scl = (j >= 11 && j <= 13) ? 1.41421356237f : 1.0f;
  const int o0 = oy*64 + tx*4;
  const int qkv = o0 / 384, rem = o0 % 384, head = rem / 48, c = rem % 48;
  const int n0 = nx*64 + ty*4;
  #pragma unroll
  for (int r = 0; r < 4; ++r) {
    int t = n0 + r;
    size_t th = (size_t)head*TT + t;
    float4 v = make_float4(acc[r][0], acc[r][1], acc[r][2], acc[r][3]);
    if (j == 0) { v.x += b_attn[o0]; v.y += b_attn[o0+1]; v.z += b_attn[o0+2]; v.w += b_attn[o0+3]; }
    ushort4 s4;
    if (qkv == 2) {
      s4.x = f2bf(v.x); s4.y = f2bf(v.y); s4.z = f2bf(v.z); s4.w = f2bf(v.w);
      *(ushort4*)(vb + th*CK + j*48 + c) = s4;
    } else {
      s4.x = f2bf(v.x*scl); s4.y = f2bf(v.y*scl); s4.z = f2bf(v.z*scl); s4.w = f2bf(v.w*scl);
      ushort* dst = (qkv == 0 ? qf : kf) + th*FF + fi*48 + c;
      *(ushort4*)dst = s4;
    }
  }
}

// ---------------- K1c: append qn/kn rank-1 features + zero padding ----------------
__global__ void k1c_extras(ushort* __restrict__ qf, ushort* __restrict__ kf) {
  int th = blockIdx.x*256 + threadIdx.x;
  if (th >= THD_B) return;
  ushort* q = qf + (size_t)th*FF;
  ushort* k = kf + (size_t)th*FF;
  float qn = 0.f, kn = 0.f;
  for (int e = 8*48; e < 11*48; ++e) {
    float a = bf2f(q[e]), b = bf2f(k[e]);
    qn += a*a; kn += b*b;
  }
  qn *= 0.5f; kn *= 0.5f;              // features hold sqrt(2)*proj
  q[528] = f2bf(qn);  q[529] = 0x3F80u;            // 1.0
  k[528] = 0xBF80u;   k[529] = f2bf(-kn);          // -1.0, -kn
  #pragma unroll
  for (int e = 530; e < FF; ++e) { q[e] = 0; k[e] = 0; }
}

// ---------------- K2e: per-head V transpose, vb[h][t][c] -> vT[h][c][t] (bf16) ----------------
__global__ __launch_bounds__(256) void k2e_vtr(const ushort* __restrict__ vb,
                                               ushort* __restrict__ vT) {
  const int h = blockIdx.z;
  const int c0 = blockIdx.x*32, t0 = blockIdx.y*32;
  __shared__ ushort s[32][36];
  const int tid = threadIdx.x;
  const int r = tid >> 3, c4 = (tid & 7)*4;
  ushort4 v = *(const ushort4*)(vb + ((size_t)h*TT + t0 + r)*CK + c0 + c4);
  s[r][c4] = v.x; s[r][c4+1] = v.y; s[r][c4+2] = v.z; s[r][c4+3] = v.w;
  __syncthreads();
  ushort4 o;
  o.x = s[c4][r]; o.y = s[c4+1][r]; o.z = s[c4+2][r]; o.w = s[c4+3][r];
  *(ushort4*)(vT + ((size_t)h*CK + c0 + r)*TT + t0 + c4) = o;
}

// ---------------- K2b: logits = (qf . kf)/sqrt(384), bf16 MFMA ----------------
// grid (8 s-tiles, 8 t-tiles, hg). 256 thr = 4 waves (2x2), wave = 64x64 out.
__global__ __launch_bounds__(256) void k2b_logits_mfma(const ushort* __restrict__ qf,
                                                       const ushort* __restrict__ kf,
                                                       float* __restrict__ logits, int hh0) {
  const int lh = blockIdx.z, h = hh0 + lh;
  const int t0 = blockIdx.y*128, s0 = blockIdx.x*128;
  const ushort* Ag = qf + (size_t)h*TT*FF;
  const ushort* Bg = kf + (size_t)h*TT*FF;
  __shared__ __align__(16) ushort As[128*32];
  __shared__ __align__(16) ushort Bs[128*32];
  const int tid = threadIdx.x;
  const int lane = tid & 63, wid = tid >> 6;
  const int wr = wid >> 1, wc = wid & 1;
  const int rr = lane & 15, kq = lane >> 4;
  const int ar = tid >> 1, ab = (tid & 1)*2;       // staging row / 16B-block base
  f32x4 acc[4][4] = {};
  for (int kk = 0; kk < FF; kk += 32) {
    __syncthreads();
    {
      const ulonglong2* ga = (const ulonglong2*)(Ag + (size_t)(t0 + ar)*FF + kk);
      const ulonglong2* gb = (const ulonglong2*)(Bg + (size_t)(s0 + ar)*FF + kk);
      ulonglong2 a0 = ga[ab], a1 = ga[ab+1], b0 = gb[ab], b1 = gb[ab+1];
      *(ulonglong2*)(&As[swzi(ar, ab)])   = a0;
      *(ulonglong2*)(&As[swzi(ar, ab+1)]) = a1;
      *(ulonglong2*)(&Bs[swzi(ar, ab)])   = b0;
      *(ulonglong2*)(&Bs[swzi(ar, ab+1)]) = b1;
    }
    __syncthreads();
    bf16x8 af[4], bfv[4];
    #pragma unroll
    for (int m = 0; m < 4; ++m) af[m]  = *(const bf16x8*)(&As[swzi(wr*64 + m*16 + rr, kq)]);
    #pragma unroll
    for (int n = 0; n < 4; ++n) bfv[n] = *(const bf16x8*)(&Bs[swzi(wc*64 + n*16 + rr, kq)]);
    #pragma unroll
    for (int m = 0; m < 4; ++m)
      #pragma unroll
      for (int n = 0; n < 4; ++n)
        acc[m][n] = __builtin_amdgcn_mfma_f32_16x16x32_bf16(af[m], bfv[n], acc[m][n], 0, 0, 0);
  }
  const float iscl = 0.051031036307982884f;   // 1/sqrt(384)
  const int cr = (lane >> 4) << 2, cc = lane & 15;
  #pragma unroll
  for (int m = 0; m < 4; ++m)
    #pragma unroll
    for (int n = 0; n < 4; ++n) {
      size_t trow = (size_t)lh*TT + t0 + wr*64 + m*16 + cr;
      float* dst = logits + trow*TT + s0 + wc*64 + n*16 + cc;
      #pragma unroll
      for (int j = 0; j < 4; ++j) dst[(size_t)j*TT] = acc[m][n][j]*iscl;
    }
}

// ---------------- K2c: row softmax, fp32 in -> bf16 probs out ----------------
__global__ __launch_bounds__(256) void k2c_softmax(const float* __restrict__ logits,
                                                   ushort* __restrict__ probs) {
  int row = blockIdx.x * 4 + (threadIdx.x >> 6);
  int lane = threadIdx.x & 63;
  const float* p = logits + (size_t)row * TT;
  ushort* pb = probs + (size_t)row * TT;
  float4 v[4];
  float mx = -1e30f;
  #pragma unroll
  for (int m = 0; m < 4; ++m) {
    v[m] = *(const float4*)(p + (m*64 + lane)*4);
    mx = fmaxf(mx, fmaxf(fmaxf(v[m].x, v[m].y), fmaxf(v[m].z, v[m].w)));
  }
  #pragma unroll
  for (int off = 32; off; off >>= 1) mx = fmaxf(mx, __shfl_xor(mx, off, 64));
  float sum = 0.f;
  #pragma unroll
  for (int m = 0; m < 4; ++m) {
    v[m].x = __expf(v[m].x - mx); v[m].y = __expf(v[m].y - mx);
    v[m].z = __expf(v[m].z - mx); v[m].w = __expf(v[m].w - mx);
    sum += v[m].x + v[m].y + v[m].z + v[m].w;
  }
  #pragma unroll
  for (int off = 32; off; off >>= 1) sum += __shfl_xor(sum, off, 64);
  float inv = 1.0f / sum;
  #pragma unroll
  for (int m = 0; m < 4; ++m) {
    ushort4 o;
    o.x = f2bf(v[m].x*inv); o.y = f2bf(v[m].y*inv);
    o.z = f2bf(v[m].z*inv); o.w = f2bf(v[m].w*inv);
    *(ushort4*)(pb + (m*64 + lane)*4) = o;
  }
}

// ---------------- K2d: ao = probs @ V, bf16 MFMA (V pre-transposed) ----------------
// grid (12 c-tiles(64), 8 t-tiles(128), hg). wave = 64t x 32c.
__global__ __launch_bounds__(256) void k2d_pv_mfma(const ushort* __restrict__ probs,
                                                   const ushort* __restrict__ vT,
                                                   float* __restrict__ ao, int hh0) {
  const int lh = blockIdx.z, h = hh0 + lh;
  const int t0 = blockIdx.y*128, c0 = blockIdx.x*64;
  const ushort* Ag = probs + (size_t)lh*TT*TT;
  const ushort* Bg = vT + (size_t)h*CK*TT;
  __shared__ __align__(16) ushort As[128*32];
  __shared__ __align__(16) ushort Bs[64*32];
  const int tid = threadIdx.x;
  const int lane = tid & 63, wid = tid >> 6;
  const int wr = wid >> 1, wc = wid & 1;
  const int rr = lane & 15, kq = lane >> 4;
  const int ar = tid >> 1, ab = (tid & 1)*2;
  const int br = (tid & 127) >> 1;
  f32x4 acc[4][2] = {};
  for (int kk = 0; kk < TT; kk += 32) {
    __syncthreads();
    {
      const ulonglong2* ga = (const ulonglong2*)(Ag + (size_t)(t0 + ar)*TT + kk);
      ulonglong2 a0 = ga[ab], a1 = ga[ab+1];
      *(ulonglong2*)(&As[swzi(ar, ab)])   = a0;
      *(ulonglong2*)(&As[swzi(ar, ab+1)]) = a1;
      if (tid < 128) {
        const ulonglong2* gb = (const ulonglong2*)(Bg + (size_t)(c0 + br)*TT + kk);
        ulonglong2 b0 = gb[ab], b1 = gb[ab+1];
        *(ulonglong2*)(&Bs[swzi(br, ab)])   = b0;
        *(ulonglong2*)(&Bs[swzi(br, ab+1)]) = b1;
      }
    }
    __syncthreads();
    bf16x8 af[4], bfv[2];
    #pragma unroll
    for (int m = 0; m < 4; ++m) af[m]  = *(const bf16x8*)(&As[swzi(wr*64 + m*16 + rr, kq)]);
    #pragma unroll
    for (int n = 0; n < 2; ++n) bfv[n] = *(const bf16x8*)(&Bs[swzi(wc*32 + n*16 + rr, kq)]);
    #pragma unroll
    for (int m = 0; m < 4; ++m)
      #pragma unroll
      for (int n = 0; n < 2; ++n)
        acc[m][n] = __builtin_amdgcn_mfma_f32_16x16x32_bf16(af[m], bfv[n], acc[m][n], 0, 0, 0);
  }
  const int cr = (lane >> 4) << 2, cc = lane & 15;
  #pragma unroll
  for (int m = 0; m < 4; ++m)
    #pragma unroll
    for (int n = 0; n < 2; ++n) {
      int t = t0 + wr*64 + m*16 + cr;
      int c = c0 + wc*32 + n*16 + cc;
      #pragma unroll
      for (int j = 0; j < 4; ++j)
        ao[(size_t)(t + j)*HCK + h*CK + c] = acc[m][n][j];
    }
}

// ---------------- K3: out-projection equi-linear + bias + residual ----------------
__global__ __launch_bounds__(256) void k3_final(const float* __restrict__ ao,
                                                const float* __restrict__ wTn,
                                                const float* __restrict__ b_next,
                                                const float* __restrict__ hidden_b,
                                                float* __restrict__ out_b) {
  const int n0 = blockIdx.x * 2;
  const int tid = threadIdx.x;
  __shared__ float aos[2][8*16*52];
  #pragma unroll
  for (int tt = 0; tt < 2; ++tt) {
    const float* src = ao + (size_t)(n0 + tt)*HCK;
    for (int idx = tid; idx < HCK/4; idx += 256) {
      int m4 = idx*4;
      int h = m4 / CK, r = m4 % CK;
      *(float4*)(&aos[tt][(h*16 + (r/48))*52 + (r%48)]) = *(const float4*)(src + m4);
    }
  }
  __syncthreads();
  const int j = tid & 15;
  const int og = tid >> 4;
  const int g = c_gj[j], e = c_ej[j], srcc = c_srcj[j];
  float accA[3] = {0.f,0.f,0.f}, accB[3] = {0.f,0.f,0.f};
  for (int h = 0; h < HH; ++h) {
    const int xbase = (h*16 + j)*52;
    const int sbase = (h*16 + srcc)*52;
    for (int c4 = 0; c4 < 48; c4 += 4) {
      float4 x0 = *(const float4*)(&aos[0][xbase + c4]);
      float4 x1 = *(const float4*)(&aos[1][xbase + c4]);
      #pragma unroll
      for (int m = 0; m < 3; ++m) {
        int o = og + m*16;
        float4 w = *(const float4*)(wTn + ((size_t)g*48 + o)*384 + h*48 + c4);
        accA[m] += w.x*x0.x + w.y*x0.y + w.z*x0.z + w.w*x0.w;
        accB[m] += w.x*x1.x + w.y*x1.y + w.z*x1.z + w.w*x1.w;
      }
      if (e >= 0) {
        float4 s0 = *(const float4*)(&aos[0][sbase + c4]);
        float4 s1 = *(const float4*)(&aos[1][sbase + c4]);
        #pragma unroll
        for (int m = 0; m < 3; ++m) {
          int o = og + m*16;
          float4 w = *(const float4*)(wTn + ((size_t)e*48 + o)*384 + h*48 + c4);
          accA[m] += w.x*s0.x + w.y*s0.y + w.z*s0.z + w.w*s0.w;
          accB[m] += w.x*s1.x + w.y*s1.y + w.z*s1.z + w.w*s1.w;
        }
      }
    }
  }
  #pragma unroll
  for (int m = 0; m < 3; ++m) {
    int o = og + m*16;
    float bb = (j == 0) ? b_next[o] : 0.f;
    size_t offA = (size_t)n0*768 + o*16 + j;
    size_t offB = (size_t)(n0+1)*768 + o*16 + j;
    out_b[offA] = accA[m] + bb + hidden_b[offA];
    out_b[offB] = accB[m] + bb + hidden_b[offB];
  }
}

extern "C" void kernel_launch(void* const* d_in, const int* in_sizes, int n_in,
                              void* d_out, int out_size, void* d_ws, size_t ws_size,
                              hipStream_t stream) {
  const float* hidden = (const float*)d_in[0];
  const float* w_attn = (const float*)d_in[1];
  const float* b_attn = (const float*)d_in[2];
  const float* w_next = (const float*)d_in[3];
  const float* b_next = (const float*)d_in[4];
  const float* ln_w   = (const float*)d_in[5];
  float* out = (float*)d_out;
  float* ws = (float*)d_ws;

  // floats: qf+kf bf16 (2*4456448/2) + vb+vT bf16 (2*6291456/2) + ao + wTa + wTn
  const size_t FIXED_FL = 4456448ull + 6291456ull + 6291456ull + 497664ull + 165888ull; // 17,702,912
  const size_t PER_HG   = 1048576ull + 524288ull;  // logits f32 + probs bf16 (in floats)
  int hg = 0;
  for (int g = 8; g >= 1; g >>= 1)
    if (ws_size >= (FIXED_FL + (size_t)g*PER_HG)*4) { hg = g; break; }
  if (hg == 0) {
    kfill<<<2048, 256, 0, stream>>>(out, (size_t)out_size, 1.0e6f);
    return;
  }

  float*  logits = ws;                                     // hg * 1M floats
  ushort* probs  = (ushort*)(ws + (size_t)hg*1048576);     // hg * 1M bf16
  float*  hT     = ws;                                     // 786K floats, aliased (dead before k2b)
  ushort* qf     = (ushort*)(ws + (size_t)hg*PER_HG);      // 8192*544
  ushort* kf     = qf + (size_t)THD_B*FF;                  // 8192*544
  ushort* vb     = kf + (size_t)THD_B*FF;                  // 8192*768
  ushort* vT     = vb + (size_t)THD_B*CK;                  // 8192*768
  float*  ao     = (float*)(vT + (size_t)THD_B*CK);        // 6,291,456 floats
  float*  wTa    = ao + 6291456;                           // 497,664
  float*  wTn    = wTa + 497664;                           // 165,888

  k0_transpose_w<<<216, 256, 0, stream>>>(w_attn, w_next, wTa, wTn);
  for (int b = 0; b < BB; ++b) {
    const float* hid_b = hidden + (size_t)b*TT*768;
    float* out_b = out + (size_t)b*TT*768;
    k1_rmsnorm<<<TT, 256, 0, stream>>>(hid_b, ln_w, hT);
    k1b_qkv<<<dim3(16, 18, 16), 256, 0, stream>>>(hT, wTa, b_attn, qf, kf, vb);
    k1c_extras<<<THD_B/256, 256, 0, stream>>>(qf, kf);
    k2e_vtr<<<dim3(CK/32, TT/32, HH), 256, 0, stream>>>(vb, vT);
    for (int hh0 = 0; hh0 < HH; hh0 += hg) {
      k2b_logits_mfma<<<dim3(8, 8, hg), 256, 0, stream>>>(qf, kf, logits, hh0);
      k2c_softmax<<<hg*256, 256, 0, stream>>>(logits, probs);
      k2d_pv_mfma<<<dim3(12, 8, hg), 256, 0, stream>>>(probs, vT, ao, hh0);
    }
    k3_final<<<TT/2, 256, 0, stream>>>(ao, wTn, b_next, hid_b, out_b);
  }
}

// Round 5
// 601.438 us; speedup vs baseline: 3.6164x; 1.4183x over previous
//
#include <hip/hip_runtime.h>
#include <math.h>

#define BB 4
#define TT 1024
#define CC 48
#define HH 8
#define THD_B (HH*TT)     // 8192 token-heads per batch
#define FF 544            // padded feature dim (528 bilinear + qn/kn + pad), 17*32
#define CK (CC*16)        // 768
#define HCK (HH*CK)       // 6144

typedef __attribute__((ext_vector_type(8))) short bf16x8;
typedef __attribute__((ext_vector_type(4))) float f32x4;

// per-component tables: grade slice, e0 slice, e0 source comp, feature index
// e0 maps move s->d: 0->1, 2->5, 3->6, 4->7, 8->11, 9->12, 10->13, 14->15
__constant__ int c_gj[16]   = {0,1,1,1,1,2,2,2,2,2,2,3,3,3,3,4};
__constant__ int c_ej[16]   = {-1,5,-1,-1,-1,6,6,6,-1,-1,-1,7,7,7,-1,8};
__constant__ int c_srcj[16] = {0,0,0,0,0,2,3,4,0,0,0,8,9,10,0,14};
__constant__ int c_fi[16]   = {0,-1,1,2,3,-1,-1,-1,4,5,6,8,9,10,7,-1};

__device__ inline ushort f2bf(float x) {           // RNE float->bf16
  union { float f; unsigned u; } a; a.f = x;
  unsigned r = a.u + 0x7FFFu + ((a.u >> 16) & 1u);
  return (ushort)(r >> 16);
}
__device__ inline float bf2f(ushort u) {
  union { unsigned u; float f; } a; a.u = ((unsigned)u) << 16; return a.f;
}
// LDS tile [rows][32 ushorts]; 16B-block XOR swizzle: blk' = blk ^ ((row>>2)&3)
__device__ inline int swzi(int row, int blk) {
  return row*32 + (((blk ^ (row >> 2)) & 3) << 3);
}

// ---------------- sentinel fill (workspace too small diagnostic) ----------------
__global__ void kfill(float* __restrict__ p, size_t n, float v) {
  size_t i = (size_t)blockIdx.x*256 + threadIdx.x;
  size_t stride = (size_t)gridDim.x*256;
  for (; i < n; i += stride) p[i] = v;
}

// ---------------- K0: transpose attn weights to slice-major ----------------
__global__ void k0_transpose_w(const float* __restrict__ w_attn,
                               float* __restrict__ wTa) {
  int idx = blockIdx.x*256 + threadIdx.x;
  if (idx < 1152*48) {
    int o = idx / 48, i = idx % 48;
    #pragma unroll
    for (int a = 0; a < 9; ++a)
      wTa[((size_t)a*1152 + o)*48 + i] = w_attn[((size_t)o*48 + i)*9 + a];
  }
}

// ---------------- K0b: per-plane out-proj weights, bf16, [j][o][768] ----------------
__global__ void k0b_wplanes(const float* __restrict__ w_next,
                            ushort* __restrict__ wBt) {
  int idx = blockIdx.x*256 + threadIdx.x;   // over 16*48*384
  if (idx >= 16*48*384) return;
  int j = idx / (48*384), rem = idx % (48*384), o = rem / 384, i = rem % 384;
  int g = c_gj[j], e = c_ej[j];
  ushort* dst = wBt + ((size_t)j*48 + o)*768;
  dst[i]       = f2bf(w_next[((size_t)o*384 + i)*9 + g]);
  dst[384 + i] = (e >= 0) ? f2bf(w_next[((size_t)o*384 + i)*9 + e]) : (ushort)0;
}

// ---------------- K1: equi RMS norm -> hT[comp][token][chan]  (per batch) ----------------
__global__ __launch_bounds__(256) void k1_rmsnorm(const float* __restrict__ hidden_b,
                                                  const float* __restrict__ lnw,
                                                  float* __restrict__ hT) {
  int n = blockIdx.x, tid = threadIdx.x;
  __shared__ float xs[768];
  __shared__ float red[256];
  float psum = 0.f;
  for (int e = tid; e < 768; e += 256) {
    float v = hidden_b[(size_t)n*768 + e];
    xs[e] = v;
    int k = e & 15;
    if ((0x471Du >> k) & 1u) psum += v*v;   // INV = {0,2,3,4,8,9,10,14}
  }
  red[tid] = psum;
  __syncthreads();
  for (int s = 128; s > 0; s >>= 1) { if (tid < s) red[tid] += red[tid+s]; __syncthreads(); }
  float scale = rsqrtf(red[0]/48.0f + 1e-6f);
  for (int e = tid; e < 768; e += 256) {
    int k = e / 48, i = e % 48;
    hT[((size_t)k*TT + n)*48 + i] = xs[i*16 + k] * scale * lnw[i];
  }
}

// ---------------- K1b: qkv equi-linear, fp32 microtile, bf16 outputs ----------------
__global__ __launch_bounds__(256) void k1b_qkv(const float* __restrict__ hT,
                                               const float* __restrict__ wTa,
                                               const float* __restrict__ b_attn,
                                               ushort* __restrict__ qf,
                                               ushort* __restrict__ kf,
                                               ushort* __restrict__ vb) {
  const int j  = blockIdx.z;
  const int fi = c_fi[j];
  const int oy = blockIdx.y;
  if (fi < 0 && oy < 12) return;        // q/k never use comps {1,5,6,7,15}
  const int nx = blockIdx.x;
  const int g = c_gj[j], e = c_ej[j], srcc = c_srcj[j];
  const int nk = (e >= 0) ? 2 : 1;
  const int KDIM = 48*nk;
  __shared__ float As[64][100];
  __shared__ float Bs[64][100];
  const int tid = threadIdx.x;
  {
    const int n0 = nx*64;
    for (int p = 0; p < nk; ++p) {
      int jp = (p == 0) ? j : srcc;
      const float* sa = hT + ((size_t)jp*TT + n0)*48;
      int a = (p == 0) ? g : e;
      const float* sb = wTa + ((size_t)a*1152 + oy*64)*48;
      for (int idx = tid; idx < 64*12; idx += 256) {
        int r = idx / 12, i4 = (idx % 12)*4;
        *(float4*)(&As[r][p*48 + i4]) = *(const float4*)(sa + (size_t)r*48 + i4);
        *(float4*)(&Bs[r][p*48 + i4]) = *(const float4*)(sb + (size_t)r*48 + i4);
      }
    }
  }
  __syncthreads();
  const int tx = tid % 16, ty = tid / 16;
  float acc[4][4] = {};
  for (int k4 = 0; k4 < KDIM; k4 += 4) {
    float4 a4[4], b4[4];
    #pragma unroll
    for (int m = 0; m < 4; ++m) a4[m] = *(const float4*)(&As[ty*4+m][k4]);
    #pragma unroll
    for (int m = 0; m < 4; ++m) b4[m] = *(const float4*)(&Bs[tx*4+m][k4]);
    #pragma unroll
    for (int r = 0; r < 4; ++r)
      #pragma unroll
      for (int c = 0; c < 4; ++c)
        acc[r][c] += a4[r].x*b4[c].x + a4[r].y*b4[c].y + a4[r].z*b4[c].z + a4[r].w*b4[c].w;
  }
  const float scl = (j >= 11 && j <= 13) ? 1.41421356237f : 1.0f;
  const int o0 = oy*64 + tx*4;
  const int qkv = o0 / 384, rem = o0 % 384, head = rem / 48, c = rem % 48;
  const int n0 = nx*64 + ty*4;
  #pragma unroll
  for (int r = 0; r < 4; ++r) {
    int t = n0 + r;
    size_t th = (size_t)head*TT + t;
    float4 v = make_float4(acc[r][0], acc[r][1], acc[r][2], acc[r][3]);
    if (j == 0) { v.x += b_attn[o0]; v.y += b_attn[o0+1]; v.z += b_attn[o0+2]; v.w += b_attn[o0+3]; }
    ushort4 s4;
    if (qkv == 2) {
      s4.x = f2bf(v.x); s4.y = f2bf(v.y); s4.z = f2bf(v.z); s4.w = f2bf(v.w);
      *(ushort4*)(vb + th*CK + j*48 + c) = s4;
    } else {
      s4.x = f2bf(v.x*scl); s4.y = f2bf(v.y*scl); s4.z = f2bf(v.z*scl); s4.w = f2bf(v.w*scl);
      ushort* dst = (qkv == 0 ? qf : kf) + th*FF + fi*48 + c;
      *(ushort4*)dst = s4;
    }
  }
}

// ---------------- K1c: qn/kn rank-1 features, one wave per token-head ----------------
__global__ __launch_bounds__(256) void k1c_extras(ushort* __restrict__ qf,
                                                  ushort* __restrict__ kf) {
  int th = blockIdx.x*4 + (threadIdx.x >> 6);
  int lane = threadIdx.x & 63;
  ushort* q = qf + (size_t)th*FF;
  ushort* k = kf + (size_t)th*FF;
  float qn = 0.f, kn = 0.f;
  if (lane < 36) {                       // elements 384..527 (sqrt2*proj planes)
    ushort4 a = *(const ushort4*)(q + 384 + lane*4);
    ushort4 b = *(const ushort4*)(k + 384 + lane*4);
    float x;
    x = bf2f(a.x); qn += x*x;  x = bf2f(a.y); qn += x*x;
    x = bf2f(a.z); qn += x*x;  x = bf2f(a.w); qn += x*x;
    x = bf2f(b.x); kn += x*x;  x = bf2f(b.y); kn += x*x;
    x = bf2f(b.z); kn += x*x;  x = bf2f(b.w); kn += x*x;
  }
  #pragma unroll
  for (int off = 32; off; off >>= 1) {
    qn += __shfl_xor(qn, off, 64);
    kn += __shfl_xor(kn, off, 64);
  }
  if (lane == 0) {                       // features hold sqrt(2)*proj -> *0.5
    q[528] = f2bf(qn*0.5f); q[529] = 0x3F80u;      // 1.0
    k[528] = 0xBF80u;       k[529] = f2bf(-kn*0.5f);
  }
  if (lane < 14) { q[530+lane] = 0; k[530+lane] = 0; }
}

// ---------------- K2e: per-head V transpose, vb[h][t][c] -> vT[h][c][t] (bf16) ----------------
__global__ __launch_bounds__(256) void k2e_vtr(const ushort* __restrict__ vb,
                                               ushort* __restrict__ vT) {
  const int h = blockIdx.z;
  const int c0 = blockIdx.x*32, t0 = blockIdx.y*32;
  __shared__ ushort s[32][36];
  const int tid = threadIdx.x;
  const int r = tid >> 3, c4 = (tid & 7)*4;
  ushort4 v = *(const ushort4*)(vb + ((size_t)h*TT + t0 + r)*CK + c0 + c4);
  s[r][c4] = v.x; s[r][c4+1] = v.y; s[r][c4+2] = v.z; s[r][c4+3] = v.w;
  __syncthreads();
  ushort4 o;
  o.x = s[c4][r]; o.y = s[c4+1][r]; o.z = s[c4+2][r]; o.w = s[c4+3][r];
  *(ushort4*)(vT + ((size_t)h*CK + c0 + r)*TT + t0 + c4) = o;
}

// ---------------- K2b: logits = (qf . kf)/sqrt(384), bf16 MFMA ----------------
__global__ __launch_bounds__(256) void k2b_logits_mfma(const ushort* __restrict__ qf,
                                                       const ushort* __restrict__ kf,
                                                       float* __restrict__ logits, int hh0) {
  const int lh = blockIdx.z, h = hh0 + lh;
  const int t0 = blockIdx.y*128, s0 = blockIdx.x*128;
  const ushort* Ag = qf + (size_t)h*TT*FF;
  const ushort* Bg = kf + (size_t)h*TT*FF;
  __shared__ __align__(16) ushort As[128*32];
  __shared__ __align__(16) ushort Bs[128*32];
  const int tid = threadIdx.x;
  const int lane = tid & 63, wid = tid >> 6;
  const int wr = wid >> 1, wc = wid & 1;
  const int rr = lane & 15, kq = lane >> 4;
  const int ar = tid >> 1, ab = (tid & 1)*2;
  f32x4 acc[4][4] = {};
  for (int kk = 0; kk < FF; kk += 32) {
    __syncthreads();
    {
      const ulonglong2* ga = (const ulonglong2*)(Ag + (size_t)(t0 + ar)*FF + kk);
      const ulonglong2* gb = (const ulonglong2*)(Bg + (size_t)(s0 + ar)*FF + kk);
      ulonglong2 a0 = ga[ab], a1 = ga[ab+1], b0 = gb[ab], b1 = gb[ab+1];
      *(ulonglong2*)(&As[swzi(ar, ab)])   = a0;
      *(ulonglong2*)(&As[swzi(ar, ab+1)]) = a1;
      *(ulonglong2*)(&Bs[swzi(ar, ab)])   = b0;
      *(ulonglong2*)(&Bs[swzi(ar, ab+1)]) = b1;
    }
    __syncthreads();
    bf16x8 af[4], bfv[4];
    #pragma unroll
    for (int m = 0; m < 4; ++m) af[m]  = *(const bf16x8*)(&As[swzi(wr*64 + m*16 + rr, kq)]);
    #pragma unroll
    for (int n = 0; n < 4; ++n) bfv[n] = *(const bf16x8*)(&Bs[swzi(wc*64 + n*16 + rr, kq)]);
    #pragma unroll
    for (int m = 0; m < 4; ++m)
      #pragma unroll
      for (int n = 0; n < 4; ++n)
        acc[m][n] = __builtin_amdgcn_mfma_f32_16x16x32_bf16(af[m], bfv[n], acc[m][n], 0, 0, 0);
  }
  const float iscl = 0.051031036307982884f;   // 1/sqrt(384)
  const int cr = (lane >> 4) << 2, cc = lane & 15;
  #pragma unroll
  for (int m = 0; m < 4; ++m)
    #pragma unroll
    for (int n = 0; n < 4; ++n) {
      size_t trow = (size_t)lh*TT + t0 + wr*64 + m*16 + cr;
      float* dst = logits + trow*TT + s0 + wc*64 + n*16 + cc;
      #pragma unroll
      for (int j = 0; j < 4; ++j) dst[(size_t)j*TT] = acc[m][n][j]*iscl;
    }
}

// ---------------- K2c: row softmax, fp32 in -> bf16 probs out ----------------
__global__ __launch_bounds__(256) void k2c_softmax(const float* __restrict__ logits,
                                                   ushort* __restrict__ probs) {
  int row = blockIdx.x * 4 + (threadIdx.x >> 6);
  int lane = threadIdx.x & 63;
  const float* p = logits + (size_t)row * TT;
  ushort* pb = probs + (size_t)row * TT;
  float4 v[4];
  float mx = -1e30f;
  #pragma unroll
  for (int m = 0; m < 4; ++m) {
    v[m] = *(const float4*)(p + (m*64 + lane)*4);
    mx = fmaxf(mx, fmaxf(fmaxf(v[m].x, v[m].y), fmaxf(v[m].z, v[m].w)));
  }
  #pragma unroll
  for (int off = 32; off; off >>= 1) mx = fmaxf(mx, __shfl_xor(mx, off, 64));
  float sum = 0.f;
  #pragma unroll
  for (int m = 0; m < 4; ++m) {
    v[m].x = __expf(v[m].x - mx); v[m].y = __expf(v[m].y - mx);
    v[m].z = __expf(v[m].z - mx); v[m].w = __expf(v[m].w - mx);
    sum += v[m].x + v[m].y + v[m].z + v[m].w;
  }
  #pragma unroll
  for (int off = 32; off; off >>= 1) sum += __shfl_xor(sum, off, 64);
  float inv = 1.0f / sum;
  #pragma unroll
  for (int m = 0; m < 4; ++m) {
    ushort4 o;
    o.x = f2bf(v[m].x*inv); o.y = f2bf(v[m].y*inv);
    o.z = f2bf(v[m].z*inv); o.w = f2bf(v[m].w*inv);
    *(ushort4*)(pb + (m*64 + lane)*4) = o;
  }
}

// ---------------- K2d: aoP[j][t][h*48+c] = probs @ V, bf16 MFMA ----------------
__global__ __launch_bounds__(256) void k2d_pv_mfma(const ushort* __restrict__ probs,
                                                   const ushort* __restrict__ vT,
                                                   ushort* __restrict__ aoP, int hh0) {
  const int lh = blockIdx.z, h = hh0 + lh;
  const int t0 = blockIdx.y*128, c0 = blockIdx.x*64;
  const ushort* Ag = probs + (size_t)lh*TT*TT;
  const ushort* Bg = vT + (size_t)h*CK*TT;
  __shared__ __align__(16) ushort As[128*32];
  __shared__ __align__(16) ushort Bs[64*32];
  const int tid = threadIdx.x;
  const int lane = tid & 63, wid = tid >> 6;
  const int wr = wid >> 1, wc = wid & 1;
  const int rr = lane & 15, kq = lane >> 4;
  const int ar = tid >> 1, ab = (tid & 1)*2;
  const int br = (tid & 127) >> 1;
  f32x4 acc[4][2] = {};
  for (int kk = 0; kk < TT; kk += 32) {
    __syncthreads();
    {
      const ulonglong2* ga = (const ulonglong2*)(Ag + (size_t)(t0 + ar)*TT + kk);
      ulonglong2 a0 = ga[ab], a1 = ga[ab+1];
      *(ulonglong2*)(&As[swzi(ar, ab)])   = a0;
      *(ulonglong2*)(&As[swzi(ar, ab+1)]) = a1;
      if (tid < 128) {
        const ulonglong2* gb = (const ulonglong2*)(Bg + (size_t)(c0 + br)*TT + kk);
        ulonglong2 b0 = gb[ab], b1 = gb[ab+1];
        *(ulonglong2*)(&Bs[swzi(br, ab)])   = b0;
        *(ulonglong2*)(&Bs[swzi(br, ab+1)]) = b1;
      }
    }
    __syncthreads();
    bf16x8 af[4], bfv[2];
    #pragma unroll
    for (int m = 0; m < 4; ++m) af[m]  = *(const bf16x8*)(&As[swzi(wr*64 + m*16 + rr, kq)]);
    #pragma unroll
    for (int n = 0; n < 2; ++n) bfv[n] = *(const bf16x8*)(&Bs[swzi(wc*32 + n*16 + rr, kq)]);
    #pragma unroll
    for (int m = 0; m < 4; ++m)
      #pragma unroll
      for (int n = 0; n < 2; ++n)
        acc[m][n] = __builtin_amdgcn_mfma_f32_16x16x32_bf16(af[m], bfv[n], acc[m][n], 0, 0, 0);
  }
  const int cr = (lane >> 4) << 2, cc = lane & 15;
  #pragma unroll
  for (int m = 0; m < 4; ++m)
    #pragma unroll
    for (int n = 0; n < 2; ++n) {
      int t = t0 + wr*64 + m*16 + cr;
      int cg = c0 + wc*32 + n*16 + cc;      // 0..767 comp-major
      int j = cg / 48, ch = cg % 48;
      ushort* dst = aoP + ((size_t)j*TT + t)*384 + h*48 + ch;
      #pragma unroll
      for (int r = 0; r < 4; ++r) dst[(size_t)r*384] = f2bf(acc[m][n][r]);
    }
}

// ---------------- K3: out-proj as 16 plane-GEMMs, bf16 MFMA + bias + residual ----------------
// grid (16 t-tiles(64), 16 j), block 256 = 4 waves; K = 768 = [ao_j ; ao_src(j)]
__global__ __launch_bounds__(256) void k3_mfma(const ushort* __restrict__ aoP,
                                               const ushort* __restrict__ wBt,
                                               const float* __restrict__ b_next,
                                               const float* __restrict__ hidden_b,
                                               float* __restrict__ out_b) {
  const int j = blockIdx.y, t0 = blockIdx.x*64;
  const int srcj = c_srcj[j];
  __shared__ __align__(16) ushort As[64*32];
  __shared__ __align__(16) ushort Bs[48*32];
  const int tid = threadIdx.x;
  const int lane = tid & 63, wid = tid >> 6;
  const int rr = lane & 15, kq = lane >> 4;
  const ushort* a0 = aoP + (size_t)j*TT*384;
  const ushort* a1 = aoP + (size_t)srcj*TT*384;
  const ushort* bw = wBt + (size_t)j*48*768;
  const int ar = tid >> 2, ac8 = (tid & 3);    // stage: 4 thr/row, 8 ushorts each
  f32x4 acc[3] = {};
  for (int kk = 0; kk < 768; kk += 32) {
    const ushort* srcA = (kk < 384) ? (a0 + kk) : (a1 + (kk - 384));
    __syncthreads();
    *(ulonglong2*)(&As[swzi(ar, ac8)]) = *(const ulonglong2*)(srcA + (size_t)(t0 + ar)*384 + ac8*8);
    if (tid < 192)
      *(ulonglong2*)(&Bs[swzi(ar, ac8)]) = *(const ulonglong2*)(bw + (size_t)ar*768 + kk + ac8*8);
    __syncthreads();
    bf16x8 af = *(const bf16x8*)(&As[swzi(wid*16 + rr, kq)]);
    #pragma unroll
    for (int n = 0; n < 3; ++n) {
      bf16x8 bf = *(const bf16x8*)(&Bs[swzi(n*16 + rr, kq)]);
      acc[n] = __builtin_amdgcn_mfma_f32_16x16x32_bf16(af, bf, acc[n], 0, 0, 0);
    }
  }
  const int cr = (lane >> 4) << 2, cc = lane & 15;
  #pragma unroll
  for (int n = 0; n < 3; ++n) {
    int o = n*16 + cc;
    float bb = (j == 0) ? b_next[o] : 0.f;
    #pragma unroll
    for (int r = 0; r < 4; ++r) {
      int t = t0 + wid*16 + cr + r;
      size_t off = (size_t)t*768 + o*16 + j;
      out_b[off] = acc[n][r] + bb + hidden_b[off];
    }
  }
}

extern "C" void kernel_launch(void* const* d_in, const int* in_sizes, int n_in,
                              void* d_out, int out_size, void* d_ws, size_t ws_size,
                              hipStream_t stream) {
  const float* hidden = (const float*)d_in[0];
  const float* w_attn = (const float*)d_in[1];
  const float* b_attn = (const float*)d_in[2];
  const float* w_next = (const float*)d_in[3];
  const float* b_next = (const float*)d_in[4];
  const float* ln_w   = (const float*)d_in[5];
  float* out = (float*)d_out;
  float* ws = (float*)d_ws;

  // floats: qf+kf bf16 + vb+vT bf16 + aoP bf16 + wTa f32 + wBt bf16
  const size_t FIXED_FL = 4456448ull + 6291456ull + 3145728ull + 497664ull + 294912ull; // 14,686,208
  const size_t PER_HG   = 1048576ull + 524288ull;  // logits f32 + probs bf16 (in floats)
  int hg = 0;
  for (int g = 8; g >= 1; g >>= 1)
    if (ws_size >= (FIXED_FL + (size_t)g*PER_HG)*4) { hg = g; break; }
  if (hg == 0) {
    kfill<<<2048, 256, 0, stream>>>(out, (size_t)out_size, 1.0e6f);
    return;
  }

  float*  logits = ws;                                     // hg * 1M floats
  ushort* probs  = (ushort*)(ws + (size_t)hg*1048576);     // hg * 1M bf16
  float*  hT     = ws;                                     // 786K floats, aliased (dead before k2b)
  ushort* qf     = (ushort*)(ws + (size_t)hg*PER_HG);      // 8192*544
  ushort* kf     = qf + (size_t)THD_B*FF;                  // 8192*544
  ushort* vb     = kf + (size_t)THD_B*FF;                  // 8192*768
  ushort* vT     = vb + (size_t)THD_B*CK;                  // 8192*768
  ushort* aoP    = vT + (size_t)THD_B*CK;                  // 16*1024*384
  float*  wTa    = (float*)(aoP + (size_t)16*TT*384);      // 497,664 f32
  ushort* wBt    = (ushort*)(wTa + 497664);                // 16*48*768

  k0_transpose_w<<<216, 256, 0, stream>>>(w_attn, wTa);
  k0b_wplanes<<<1152, 256, 0, stream>>>(w_next, wBt);
  for (int b = 0; b < BB; ++b) {
    const float* hid_b = hidden + (size_t)b*TT*768;
    float* out_b = out + (size_t)b*TT*768;
    k1_rmsnorm<<<TT, 256, 0, stream>>>(hid_b, ln_w, hT);
    k1b_qkv<<<dim3(16, 18, 16), 256, 0, stream>>>(hT, wTa, b_attn, qf, kf, vb);
    k1c_extras<<<THD_B/4, 256, 0, stream>>>(qf, kf);
    k2e_vtr<<<dim3(CK/32, TT/32, HH), 256, 0, stream>>>(vb, vT);
    for (int hh0 = 0; hh0 < HH; hh0 += hg) {
      k2b_logits_mfma<<<dim3(8, 8, hg), 256, 0, stream>>>(qf, kf, logits, hh0);
      k2c_softmax<<<hg*256, 256, 0, stream>>>(logits, probs);
      k2d_pv_mfma<<<dim3(12, 8, hg), 256, 0, stream>>>(probs, vT, aoP, hh0);
    }
    k3_mfma<<<dim3(16, 16), 256, 0, stream>>>(aoP, wBt, b_next, hid_b, out_b);
  }
}

// Round 7
// 473.775 us; speedup vs baseline: 4.5908x; 1.2695x over previous
//
#include <hip/hip_runtime.h>
#include <math.h>

#define BB 4
#define TT 1024
#define CC 48
#define HH 8
#define THD_B (HH*TT)     // 8192 token-heads per batch
#define FF 544            // padded feature dim (528 bilinear + qn/kn + pad), 17*32
#define CK (CC*16)        // 768
#define HCK (HH*CK)       // 6144

typedef __attribute__((ext_vector_type(8))) short bf16x8;
typedef __attribute__((ext_vector_type(4))) float f32x4;

// per-component tables: grade slice, e0 slice, e0 source comp, feature index
// e0 maps move s->d: 0->1, 2->5, 3->6, 4->7, 8->11, 9->12, 10->13, 14->15
__constant__ int c_gj[16]   = {0,1,1,1,1,2,2,2,2,2,2,3,3,3,3,4};
__constant__ int c_ej[16]   = {-1,5,-1,-1,-1,6,6,6,-1,-1,-1,7,7,7,-1,8};
__constant__ int c_srcj[16] = {0,0,0,0,0,2,3,4,0,0,0,8,9,10,0,14};
__constant__ int c_fi[16]   = {0,-1,1,2,3,-1,-1,-1,4,5,6,8,9,10,7,-1};

__device__ inline ushort f2bf(float x) {           // RNE float->bf16
  union { float f; unsigned u; } a; a.f = x;
  unsigned r = a.u + 0x7FFFu + ((a.u >> 16) & 1u);
  return (ushort)(r >> 16);
}
__device__ inline float bf2f(ushort u) {
  union { unsigned u; float f; } a; a.u = ((unsigned)u) << 16; return a.f;
}
// LDS tile [rows][32 ushorts]; 16B-block XOR swizzle: blk' = blk ^ ((row>>2)&3)
__device__ inline int swzi(int row, int blk) {
  return row*32 + (((blk ^ (row >> 2)) & 3) << 3);
}

// ---------------- sentinel fill (workspace too small diagnostic) ----------------
__global__ void kfill(float* __restrict__ p, size_t n, float v) {
  size_t i = (size_t)blockIdx.x*256 + threadIdx.x;
  size_t stride = (size_t)gridDim.x*256;
  for (; i < n; i += stride) p[i] = v;
}

// ---------------- K0b: per-plane out-proj weights, bf16, [j][o][768] ----------------
__global__ void k0b_wplanes(const float* __restrict__ w_next,
                            ushort* __restrict__ wBt) {
  int idx = blockIdx.x*256 + threadIdx.x;   // over 16*48*384
  if (idx >= 16*48*384) return;
  int j = idx / (48*384), rem = idx % (48*384), o = rem / 384, i = rem % 384;
  int g = c_gj[j], e = c_ej[j];
  ushort* dst = wBt + ((size_t)j*48 + o)*768;
  dst[i]       = f2bf(w_next[((size_t)o*384 + i)*9 + g]);
  dst[384 + i] = (e >= 0) ? f2bf(w_next[((size_t)o*384 + i)*9 + e]) : (ushort)0;
}

// ---------------- K0c: per-plane qkv weights, bf16, [j][o(1152)][96] ----------------
// second 48-slice = e-plane weights (0 if none); sqrt2 folded for q/k of j in 11..13
__global__ void k0c_wqkv(const float* __restrict__ w_attn,
                         ushort* __restrict__ wB) {
  int idx = blockIdx.x*256 + threadIdx.x;   // over 16*1152*48
  if (idx >= 16*1152*48) return;
  int j = idx / (1152*48), rem = idx % (1152*48), o = rem / 48, i = rem % 48;
  int g = c_gj[j], e = c_ej[j];
  float scl = (j >= 11 && j <= 13 && o < 768) ? 1.41421356237f : 1.0f;
  ushort* dst = wB + ((size_t)j*1152 + o)*96;
  dst[i]      = f2bf(w_attn[((size_t)o*48 + i)*9 + g] * scl);
  dst[48 + i] = (e >= 0) ? f2bf(w_attn[((size_t)o*48 + i)*9 + e] * scl) : (ushort)0;
}

// ---------------- K1: equi RMS norm -> hTb[comp][token][chan] (bf16, per batch) ----------------
__global__ __launch_bounds__(256) void k1_rmsnorm(const float* __restrict__ hidden_b,
                                                  const float* __restrict__ lnw,
                                                  ushort* __restrict__ hTb) {
  int n = blockIdx.x, tid = threadIdx.x;
  __shared__ float xs[768];
  __shared__ float red[256];
  float psum = 0.f;
  for (int e = tid; e < 768; e += 256) {
    float v = hidden_b[(size_t)n*768 + e];
    xs[e] = v;
    int k = e & 15;
    if ((0x471Du >> k) & 1u) psum += v*v;   // INV = {0,2,3,4,8,9,10,14}
  }
  red[tid] = psum;
  __syncthreads();
  for (int s = 128; s > 0; s >>= 1) { if (tid < s) red[tid] += red[tid+s]; __syncthreads(); }
  float scale = rsqrtf(red[0]/48.0f + 1e-6f);
  for (int e = tid; e < 768; e += 256) {
    int k = e / 48, i = e % 48;
    hTb[((size_t)k*TT + n)*48 + i] = f2bf(xs[i*16 + k] * scale * lnw[i]);
  }
}

// ---------------- K1b: qkv equi-linear, bf16 MFMA plane-GEMMs ----------------
// grid (8 t-tiles(128), 9 o-tiles(128), 16 j); C[t][o] = [hTb_j | hTb_src] @ wB_j^T
__global__ __launch_bounds__(256) void k1b_qkv_mfma(const ushort* __restrict__ hTb,
                                                    const ushort* __restrict__ wB,
                                                    const float* __restrict__ b_attn,
                                                    ushort* __restrict__ qf,
                                                    ushort* __restrict__ kf,
                                                    ushort* __restrict__ vb) {
  const int j = blockIdx.z;
  const int oy = blockIdx.y;
  const int fi = c_fi[j];
  if (fi < 0 && oy < 6) return;            // q/k never use comps {1,5,6,7,15}
  const int t0 = blockIdx.x*128, o0 = oy*128;
  const int srcj = c_srcj[j];
  __shared__ __align__(16) ushort As[128*104];   // pad 104: 2-way frag reads
  __shared__ __align__(16) ushort Bs[128*104];
  const int tid = threadIdx.x;
  const int lane = tid & 63, wid = tid >> 6;
  const int wr = wid >> 1, wc = wid & 1;
  const int rr = lane & 15, kq = lane >> 4;
  {
    const int r = tid >> 1, half = tid & 1;
    const ushort* sa = hTb + ((size_t)(half ? srcj : j)*TT + t0 + r)*48;
    const ushort* sb = wB + ((size_t)j*1152 + o0 + r)*96 + half*48;
    #pragma unroll
    for (int i = 0; i < 6; ++i) {          // 48 ushorts = 6 x 16B chunks (was 3: NaN bug)
      *(ulonglong2*)(&As[r*104 + half*48 + i*8]) = *(const ulonglong2*)(sa + i*8);
      *(ulonglong2*)(&Bs[r*104 + half*48 + i*8]) = *(const ulonglong2*)(sb + i*8);
    }
  }
  __syncthreads();
  f32x4 acc[4][4] = {};
  #pragma unroll
  for (int ks = 0; ks < 3; ++ks) {
    bf16x8 af[4], bfv[4];
    #pragma unroll
    for (int m = 0; m < 4; ++m)
      af[m] = *(const bf16x8*)(&As[(wr*64 + m*16 + rr)*104 + ks*32 + kq*8]);
    #pragma unroll
    for (int n = 0; n < 4; ++n)
      bfv[n] = *(const bf16x8*)(&Bs[(wc*64 + n*16 + rr)*104 + ks*32 + kq*8]);
    #pragma unroll
    for (int m = 0; m < 4; ++m)
      #pragma unroll
      for (int n = 0; n < 4; ++n)
        acc[m][n] = __builtin_amdgcn_mfma_f32_16x16x32_bf16(af[m], bfv[n], acc[m][n], 0, 0, 0);
  }
  const int cr = (lane >> 4) << 2, cc = lane & 15;
  #pragma unroll
  for (int n = 0; n < 4; ++n) {
    const int o = o0 + wc*64 + n*16 + cc;
    const int qkv = o / 384, rem = o % 384, head = rem / 48, c = rem % 48;
    const float bias = (j == 0) ? b_attn[o] : 0.f;
    ushort* dst;
    size_t rstride;
    if (qkv == 2) { dst = vb + ((size_t)head*TT)*CK + j*48 + c;  rstride = CK; }
    else { dst = (qkv == 0 ? qf : kf) + ((size_t)head*TT)*FF + fi*48 + c; rstride = FF; }
    #pragma unroll
    for (int m = 0; m < 4; ++m) {
      const int tb = t0 + wr*64 + m*16 + cr;
      #pragma unroll
      for (int r = 0; r < 4; ++r)
        dst[(size_t)(tb + r)*rstride] = f2bf(acc[m][n][r] + bias);
    }
  }
}

// ---------------- K1c: qn/kn rank-1 features, one wave per token-head ----------------
__global__ __launch_bounds__(256) void k1c_extras(ushort* __restrict__ qf,
                                                  ushort* __restrict__ kf) {
  int th = blockIdx.x*4 + (threadIdx.x >> 6);
  int lane = threadIdx.x & 63;
  ushort* q = qf + (size_t)th*FF;
  ushort* k = kf + (size_t)th*FF;
  float qn = 0.f, kn = 0.f;
  if (lane < 36) {                       // elements 384..527 (sqrt2*proj planes)
    ushort4 a = *(const ushort4*)(q + 384 + lane*4);
    ushort4 b = *(const ushort4*)(k + 384 + lane*4);
    float x;
    x = bf2f(a.x); qn += x*x;  x = bf2f(a.y); qn += x*x;
    x = bf2f(a.z); qn += x*x;  x = bf2f(a.w); qn += x*x;
    x = bf2f(b.x); kn += x*x;  x = bf2f(b.y); kn += x*x;
    x = bf2f(b.z); kn += x*x;  x = bf2f(b.w); kn += x*x;
  }
  #pragma unroll
  for (int off = 32; off; off >>= 1) {
    qn += __shfl_xor(qn, off, 64);
    kn += __shfl_xor(kn, off, 64);
  }
  if (lane == 0) {                       // features hold sqrt(2)*proj -> *0.5
    q[528] = f2bf(qn*0.5f); q[529] = 0x3F80u;      // 1.0
    k[528] = 0xBF80u;       k[529] = f2bf(-kn*0.5f);
  }
  if (lane < 14) { q[530+lane] = 0; k[530+lane] = 0; }
}

// ---------------- K2e: per-head V transpose, vb[h][t][c] -> vT[h][c][t] (bf16) ----------------
__global__ __launch_bounds__(256) void k2e_vtr(const ushort* __restrict__ vb,
                                               ushort* __restrict__ vT) {
  const int h = blockIdx.z;
  const int c0 = blockIdx.x*32, t0 = blockIdx.y*32;
  __shared__ ushort s[32][36];
  const int tid = threadIdx.x;
  const int r = tid >> 3, c4 = (tid & 7)*4;
  ushort4 v = *(const ushort4*)(vb + ((size_t)h*TT + t0 + r)*CK + c0 + c4);
  s[r][c4] = v.x; s[r][c4+1] = v.y; s[r][c4+2] = v.z; s[r][c4+3] = v.w;
  __syncthreads();
  ushort4 o;
  o.x = s[c4][r]; o.y = s[c4+1][r]; o.z = s[c4+2][r]; o.w = s[c4+3][r];
  *(ushort4*)(vT + ((size_t)h*CK + c0 + r)*TT + t0 + c4) = o;
}

// ---------------- K2b: logits = (qf . kf)/sqrt(384), bf16 MFMA ----------------
__global__ __launch_bounds__(256) void k2b_logits_mfma(const ushort* __restrict__ qf,
                                                       const ushort* __restrict__ kf,
                                                       float* __restrict__ logits, int hh0) {
  const int lh = blockIdx.z, h = hh0 + lh;
  const int t0 = blockIdx.y*128, s0 = blockIdx.x*128;
  const ushort* Ag = qf + (size_t)h*TT*FF;
  const ushort* Bg = kf + (size_t)h*TT*FF;
  __shared__ __align__(16) ushort As[128*32];
  __shared__ __align__(16) ushort Bs[128*32];
  const int tid = threadIdx.x;
  const int lane = tid & 63, wid = tid >> 6;
  const int wr = wid >> 1, wc = wid & 1;
  const int rr = lane & 15, kq = lane >> 4;
  const int ar = tid >> 1, ab = (tid & 1)*2;
  f32x4 acc[4][4] = {};
  for (int kk = 0; kk < FF; kk += 32) {
    __syncthreads();
    {
      const ulonglong2* ga = (const ulonglong2*)(Ag + (size_t)(t0 + ar)*FF + kk);
      const ulonglong2* gb = (const ulonglong2*)(Bg + (size_t)(s0 + ar)*FF + kk);
      ulonglong2 a0 = ga[ab], a1 = ga[ab+1], b0 = gb[ab], b1 = gb[ab+1];
      *(ulonglong2*)(&As[swzi(ar, ab)])   = a0;
      *(ulonglong2*)(&As[swzi(ar, ab+1)]) = a1;
      *(ulonglong2*)(&Bs[swzi(ar, ab)])   = b0;
      *(ulonglong2*)(&Bs[swzi(ar, ab+1)]) = b1;
    }
    __syncthreads();
    bf16x8 af[4], bfv[4];
    #pragma unroll
    for (int m = 0; m < 4; ++m) af[m]  = *(const bf16x8*)(&As[swzi(wr*64 + m*16 + rr, kq)]);
    #pragma unroll
    for (int n = 0; n < 4; ++n) bfv[n] = *(const bf16x8*)(&Bs[swzi(wc*64 + n*16 + rr, kq)]);
    #pragma unroll
    for (int m = 0; m < 4; ++m)
      #pragma unroll
      for (int n = 0; n < 4; ++n)
        acc[m][n] = __builtin_amdgcn_mfma_f32_16x16x32_bf16(af[m], bfv[n], acc[m][n], 0, 0, 0);
  }
  const float iscl = 0.051031036307982884f;   // 1/sqrt(384)
  const int cr = (lane >> 4) << 2, cc = lane & 15;
  #pragma unroll
  for (int m = 0; m < 4; ++m)
    #pragma unroll
    for (int n = 0; n < 4; ++n) {
      size_t trow = (size_t)lh*TT + t0 + wr*64 + m*16 + cr;
      float* dst = logits + trow*TT + s0 + wc*64 + n*16 + cc;
      #pragma unroll
      for (int j = 0; j < 4; ++j) dst[(size_t)j*TT] = acc[m][n][j]*iscl;
    }
}

// ---------------- K2c: row softmax, fp32 in -> bf16 probs out ----------------
__global__ __launch_bounds__(256) void k2c_softmax(const float* __restrict__ logits,
                                                   ushort* __restrict__ probs) {
  int row = blockIdx.x * 4 + (threadIdx.x >> 6);
  int lane = threadIdx.x & 63;
  const float* p = logits + (size_t)row * TT;
  ushort* pb = probs + (size_t)row * TT;
  float4 v[4];
  float mx = -1e30f;
  #pragma unroll
  for (int m = 0; m < 4; ++m) {
    v[m] = *(const float4*)(p + (m*64 + lane)*4);
    mx = fmaxf(mx, fmaxf(fmaxf(v[m].x, v[m].y), fmaxf(v[m].z, v[m].w)));
  }
  #pragma unroll
  for (int off = 32; off; off >>= 1) mx = fmaxf(mx, __shfl_xor(mx, off, 64));
  float sum = 0.f;
  #pragma unroll
  for (int m = 0; m < 4; ++m) {
    v[m].x = __expf(v[m].x - mx); v[m].y = __expf(v[m].y - mx);
    v[m].z = __expf(v[m].z - mx); v[m].w = __expf(v[m].w - mx);
    sum += v[m].x + v[m].y + v[m].z + v[m].w;
  }
  #pragma unroll
  for (int off = 32; off; off >>= 1) sum += __shfl_xor(sum, off, 64);
  float inv = 1.0f / sum;
  #pragma unroll
  for (int m = 0; m < 4; ++m) {
    ushort4 o;
    o.x = f2bf(v[m].x*inv); o.y = f2bf(v[m].y*inv);
    o.z = f2bf(v[m].z*inv); o.w = f2bf(v[m].w*inv);
    *(ushort4*)(pb + (m*64 + lane)*4) = o;
  }
}

// ---------------- K2d: aoP[j][t][h*48+c] = probs @ V, bf16 MFMA ----------------
__global__ __launch_bounds__(256) void k2d_pv_mfma(const ushort* __restrict__ probs,
                                                   const ushort* __restrict__ vT,
                                                   ushort* __restrict__ aoP, int hh0) {
  const int lh = blockIdx.z, h = hh0 + lh;
  const int t0 = blockIdx.y*128, c0 = blockIdx.x*64;
  const ushort* Ag = probs + (size_t)lh*TT*TT;
  const ushort* Bg = vT + (size_t)h*CK*TT;
  __shared__ __align__(16) ushort As[128*32];
  __shared__ __align__(16) ushort Bs[64*32];
  const int tid = threadIdx.x;
  const int lane = tid & 63, wid = tid >> 6;
  const int wr = wid >> 1, wc = wid & 1;
  const int rr = lane & 15, kq = lane >> 4;
  const int ar = tid >> 1, ab = (tid & 1)*2;
  const int br = (tid & 127) >> 1;
  f32x4 acc[4][2] = {};
  for (int kk = 0; kk < TT; kk += 32) {
    __syncthreads();
    {
      const ulonglong2* ga = (const ulonglong2*)(Ag + (size_t)(t0 + ar)*TT + kk);
      ulonglong2 a0 = ga[ab], a1 = ga[ab+1];
      *(ulonglong2*)(&As[swzi(ar, ab)])   = a0;
      *(ulonglong2*)(&As[swzi(ar, ab+1)]) = a1;
      if (tid < 128) {
        const ulonglong2* gb = (const ulonglong2*)(Bg + (size_t)(c0 + br)*TT + kk);
        ulonglong2 b0 = gb[ab], b1 = gb[ab+1];
        *(ulonglong2*)(&Bs[swzi(br, ab)])   = b0;
        *(ulonglong2*)(&Bs[swzi(br, ab+1)]) = b1;
      }
    }
    __syncthreads();
    bf16x8 af[4], bfv[2];
    #pragma unroll
    for (int m = 0; m < 4; ++m) af[m]  = *(const bf16x8*)(&As[swzi(wr*64 + m*16 + rr, kq)]);
    #pragma unroll
    for (int n = 0; n < 2; ++n) bfv[n] = *(const bf16x8*)(&Bs[swzi(wc*32 + n*16 + rr, kq)]);
    #pragma unroll
    for (int m = 0; m < 4; ++m)
      #pragma unroll
      for (int n = 0; n < 2; ++n)
        acc[m][n] = __builtin_amdgcn_mfma_f32_16x16x32_bf16(af[m], bfv[n], acc[m][n], 0, 0, 0);
  }
  const int cr = (lane >> 4) << 2, cc = lane & 15;
  #pragma unroll
  for (int m = 0; m < 4; ++m)
    #pragma unroll
    for (int n = 0; n < 2; ++n) {
      int t = t0 + wr*64 + m*16 + cr;
      int cg = c0 + wc*32 + n*16 + cc;      // 0..767 comp-major
      int j = cg / 48, ch = cg % 48;
      ushort* dst = aoP + ((size_t)j*TT + t)*384 + h*48 + ch;
      #pragma unroll
      for (int r = 0; r < 4; ++r) dst[(size_t)r*384] = f2bf(acc[m][n][r]);
    }
}

// ---------------- K3: out-proj as 16 plane-GEMMs, bf16 MFMA + bias + residual ----------------
__global__ __launch_bounds__(256) void k3_mfma(const ushort* __restrict__ aoP,
                                               const ushort* __restrict__ wBt,
                                               const float* __restrict__ b_next,
                                               const float* __restrict__ hidden_b,
                                               float* __restrict__ out_b) {
  const int j = blockIdx.y, t0 = blockIdx.x*64;
  const int srcj = c_srcj[j];
  __shared__ __align__(16) ushort As[64*32];
  __shared__ __align__(16) ushort Bs[48*32];
  const int tid = threadIdx.x;
  const int lane = tid & 63, wid = tid >> 6;
  const int rr = lane & 15, kq = lane >> 4;
  const ushort* a0 = aoP + (size_t)j*TT*384;
  const ushort* a1 = aoP + (size_t)srcj*TT*384;
  const ushort* bw = wBt + (size_t)j*48*768;
  const int ar = tid >> 2, ac8 = (tid & 3);    // stage: 4 thr/row, 8 ushorts each
  f32x4 acc[3] = {};
  for (int kk = 0; kk < 768; kk += 32) {
    const ushort* srcA = (kk < 384) ? (a0 + kk) : (a1 + (kk - 384));
    __syncthreads();
    *(ulonglong2*)(&As[swzi(ar, ac8)]) = *(const ulonglong2*)(srcA + (size_t)(t0 + ar)*384 + ac8*8);
    if (tid < 192)
      *(ulonglong2*)(&Bs[swzi(ar, ac8)]) = *(const ulonglong2*)(bw + (size_t)ar*768 + kk + ac8*8);
    __syncthreads();
    bf16x8 af = *(const bf16x8*)(&As[swzi(wid*16 + rr, kq)]);
    #pragma unroll
    for (int n = 0; n < 3; ++n) {
      bf16x8 bf = *(const bf16x8*)(&Bs[swzi(n*16 + rr, kq)]);
      acc[n] = __builtin_amdgcn_mfma_f32_16x16x32_bf16(af, bf, acc[n], 0, 0, 0);
    }
  }
  const int cr = (lane >> 4) << 2, cc = lane & 15;
  #pragma unroll
  for (int n = 0; n < 3; ++n) {
    int o = n*16 + cc;
    float bb = (j == 0) ? b_next[o] : 0.f;
    #pragma unroll
    for (int r = 0; r < 4; ++r) {
      int t = t0 + wid*16 + cr + r;
      size_t off = (size_t)t*768 + o*16 + j;
      out_b[off] = acc[n][r] + bb + hidden_b[off];
    }
  }
}

extern "C" void kernel_launch(void* const* d_in, const int* in_sizes, int n_in,
                              void* d_out, int out_size, void* d_ws, size_t ws_size,
                              hipStream_t stream) {
  const float* hidden = (const float*)d_in[0];
  const float* w_attn = (const float*)d_in[1];
  const float* b_attn = (const float*)d_in[2];
  const float* w_next = (const float*)d_in[3];
  const float* b_next = (const float*)d_in[4];
  const float* ln_w   = (const float*)d_in[5];
  float* out = (float*)d_out;
  float* ws = (float*)d_ws;

  // floats: qf+kf + vb+vT + aoP + wBt(k3) + wB(qkv) + hTb (all bf16 except logits)
  const size_t FIXED_FL = 4456448ull + 6291456ull + 3145728ull + 294912ull
                        + 884736ull + 393216ull;   // 15,466,496
  const size_t PER_HG   = 1048576ull + 524288ull;  // logits f32 + probs bf16 (in floats)
  int hg = 0;
  for (int g = 8; g >= 1; g >>= 1)
    if (ws_size >= (FIXED_FL + (size_t)g*PER_HG)*4) { hg = g; break; }
  if (hg == 0) {
    kfill<<<2048, 256, 0, stream>>>(out, (size_t)out_size, 1.0e6f);
    return;
  }

  float*  logits = ws;                                     // hg * 1M floats
  ushort* probs  = (ushort*)(ws + (size_t)hg*1048576);     // hg * 1M bf16
  ushort* qf     = (ushort*)(ws + (size_t)hg*PER_HG);      // 8192*544
  ushort* kf     = qf + (size_t)THD_B*FF;                  // 8192*544
  ushort* vb     = kf + (size_t)THD_B*FF;                  // 8192*768
  ushort* vT     = vb + (size_t)THD_B*CK;                  // 8192*768
  ushort* aoP    = vT + (size_t)THD_B*CK;                  // 16*1024*384
  ushort* wBt    = aoP + (size_t)16*TT*384;                // 16*48*768
  ushort* wB     = wBt + (size_t)16*48*768;                // 16*1152*96
  ushort* hTb    = wB + (size_t)16*1152*96;                // 16*1024*48

  k0b_wplanes<<<1152, 256, 0, stream>>>(w_next, wBt);
  k0c_wqkv<<<3456, 256, 0, stream>>>(w_attn, wB);
  for (int b = 0; b < BB; ++b) {
    const float* hid_b = hidden + (size_t)b*TT*768;
    float* out_b = out + (size_t)b*TT*768;
    k1_rmsnorm<<<TT, 256, 0, stream>>>(hid_b, ln_w, hTb);
    k1b_qkv_mfma<<<dim3(8, 9, 16), 256, 0, stream>>>(hTb, wB, b_attn, qf, kf, vb);
    k1c_extras<<<THD_B/4, 256, 0, stream>>>(qf, kf);
    k2e_vtr<<<dim3(CK/32, TT/32, HH), 256, 0, stream>>>(vb, vT);
    for (int hh0 = 0; hh0 < HH; hh0 += hg) {
      k2b_logits_mfma<<<dim3(8, 8, hg), 256, 0, stream>>>(qf, kf, logits, hh0);
      k2c_softmax<<<hg*256, 256, 0, stream>>>(logits, probs);
      k2d_pv_mfma<<<dim3(12, 8, hg), 256, 0, stream>>>(probs, vT, aoP, hh0);
    }
    k3_mfma<<<dim3(16, 16), 256, 0, stream>>>(aoP, wBt, b_next, hid_b, out_b);
  }
}

// Round 8
// 453.299 us; speedup vs baseline: 4.7982x; 1.0452x over previous
//
#include <hip/hip_runtime.h>
#include <math.h>

#define BB 4
#define TT 1024
#define CC 48
#define HH 8
#define THD_B (HH*TT)     // 8192 token-heads per batch
#define FF 576            // padded feature dim (528 bilinear + qn/kn + pad), 9*64
#define CK (CC*16)        // 768

typedef __attribute__((ext_vector_type(8))) short bf16x8;
typedef __attribute__((ext_vector_type(4))) float f32x4;

// per-component tables: grade slice, e0 slice, e0 source comp, feature index
// e0 maps move s->d: 0->1, 2->5, 3->6, 4->7, 8->11, 9->12, 10->13, 14->15
__constant__ int c_gj[16]   = {0,1,1,1,1,2,2,2,2,2,2,3,3,3,3,4};
__constant__ int c_ej[16]   = {-1,5,-1,-1,-1,6,6,6,-1,-1,-1,7,7,7,-1,8};
__constant__ int c_srcj[16] = {0,0,0,0,0,2,3,4,0,0,0,8,9,10,0,14};
__constant__ int c_fi[16]   = {0,-1,1,2,3,-1,-1,-1,4,5,6,8,9,10,7,-1};

__device__ inline ushort f2bf(float x) {           // RNE float->bf16
  union { float f; unsigned u; } a; a.f = x;
  unsigned r = a.u + 0x7FFFu + ((a.u >> 16) & 1u);
  return (ushort)(r >> 16);
}
__device__ inline float bf2f(ushort u) {
  union { unsigned u; float f; } a; a.u = ((unsigned)u) << 16; return a.f;
}
// LDS tile [rows][64 ushorts]; 16B-chunk XOR swizzle on low 2 bits
__device__ inline int swz64(int row, int chunk) {
  return row*64 + (((chunk & 4) | ((chunk ^ (row >> 2)) & 3)) << 3);
}

// ---------------- sentinel fill (workspace too small diagnostic) ----------------
__global__ void kfill(float* __restrict__ p, size_t n, float v) {
  size_t i = (size_t)blockIdx.x*256 + threadIdx.x;
  size_t stride = (size_t)gridDim.x*256;
  for (; i < n; i += stride) p[i] = v;
}

// ---------------- K0b: per-plane out-proj weights, bf16, [j][o][768] ----------------
__global__ void k0b_wplanes(const float* __restrict__ w_next,
                            ushort* __restrict__ wBt) {
  int idx = blockIdx.x*256 + threadIdx.x;   // over 16*48*384
  if (idx >= 16*48*384) return;
  int j = idx / (48*384), rem = idx % (48*384), o = rem / 384, i = rem % 384;
  int g = c_gj[j], e = c_ej[j];
  ushort* dst = wBt + ((size_t)j*48 + o)*768;
  dst[i]       = f2bf(w_next[((size_t)o*384 + i)*9 + g]);
  dst[384 + i] = (e >= 0) ? f2bf(w_next[((size_t)o*384 + i)*9 + e]) : (ushort)0;
}

// ---------------- K0c: per-plane qkv weights, bf16, [j][o(1152)][96] ----------------
__global__ void k0c_wqkv(const float* __restrict__ w_attn,
                         ushort* __restrict__ wB) {
  int idx = blockIdx.x*256 + threadIdx.x;   // over 16*1152*48
  if (idx >= 16*1152*48) return;
  int j = idx / (1152*48), rem = idx % (1152*48), o = rem / 48, i = rem % 48;
  int g = c_gj[j], e = c_ej[j];
  float scl = (j >= 11 && j <= 13 && o < 768) ? 1.41421356237f : 1.0f;
  ushort* dst = wB + ((size_t)j*1152 + o)*96;
  dst[i]      = f2bf(w_attn[((size_t)o*48 + i)*9 + g] * scl);
  dst[48 + i] = (e >= 0) ? f2bf(w_attn[((size_t)o*48 + i)*9 + e] * scl) : (ushort)0;
}

// ---------------- K1: equi RMS norm -> hTb[comp][token][chan] (bf16, per batch) ----------------
__global__ __launch_bounds__(256) void k1_rmsnorm(const float* __restrict__ hidden_b,
                                                  const float* __restrict__ lnw,
                                                  ushort* __restrict__ hTb) {
  int n = blockIdx.x, tid = threadIdx.x;
  __shared__ float xs[768];
  __shared__ float red[256];
  float psum = 0.f;
  for (int e = tid; e < 768; e += 256) {
    float v = hidden_b[(size_t)n*768 + e];
    xs[e] = v;
    int k = e & 15;
    if ((0x471Du >> k) & 1u) psum += v*v;   // INV = {0,2,3,4,8,9,10,14}
  }
  red[tid] = psum;
  __syncthreads();
  for (int s = 128; s > 0; s >>= 1) { if (tid < s) red[tid] += red[tid+s]; __syncthreads(); }
  float scale = rsqrtf(red[0]/48.0f + 1e-6f);
  for (int e = tid; e < 768; e += 256) {
    int k = e / 48, i = e % 48;
    hTb[((size_t)k*TT + n)*48 + i] = f2bf(xs[i*16 + k] * scale * lnw[i]);
  }
}

// ---------------- K1b: qkv equi-linear, bf16 MFMA plane-GEMMs ----------------
// grid (8 t-tiles(128), 9 o-tiles(128), 16 j); writes qf/kf (coalesced) and vT (transposed)
__global__ __launch_bounds__(256) void k1b_qkv_mfma(const ushort* __restrict__ hTb,
                                                    const ushort* __restrict__ wB,
                                                    const float* __restrict__ b_attn,
                                                    ushort* __restrict__ qf,
                                                    ushort* __restrict__ kf,
                                                    ushort* __restrict__ vT) {
  const int j = blockIdx.z;
  const int oy = blockIdx.y;
  const int fi = c_fi[j];
  if (fi < 0 && oy < 6) return;            // q/k never use comps {1,5,6,7,15}
  const int t0 = blockIdx.x*128, o0 = oy*128;
  const int srcj = c_srcj[j];
  __shared__ __align__(16) ushort smem[2*128*104];   // As | Bs, reused as E
  ushort* As = smem;
  ushort* Bs = smem + 128*104;
  const int tid = threadIdx.x;
  const int lane = tid & 63, wid = tid >> 6;
  const int wr = wid >> 1, wc = wid & 1;
  const int rr = lane & 15, kq = lane >> 4;
  {
    const int r = tid >> 1, half = tid & 1;
    const ushort* sa = hTb + ((size_t)(half ? srcj : j)*TT + t0 + r)*48;
    const ushort* sb = wB + ((size_t)j*1152 + o0 + r)*96 + half*48;
    #pragma unroll
    for (int i = 0; i < 6; ++i) {          // 48 ushorts = 6 x 16B chunks
      *(ulonglong2*)(&As[r*104 + half*48 + i*8]) = *(const ulonglong2*)(sa + i*8);
      *(ulonglong2*)(&Bs[r*104 + half*48 + i*8]) = *(const ulonglong2*)(sb + i*8);
    }
  }
  __syncthreads();
  f32x4 acc[4][4] = {};
  #pragma unroll
  for (int ks = 0; ks < 3; ++ks) {
    bf16x8 af[4], bfv[4];
    #pragma unroll
    for (int m = 0; m < 4; ++m)
      af[m] = *(const bf16x8*)(&As[(wr*64 + m*16 + rr)*104 + ks*32 + kq*8]);
    #pragma unroll
    for (int n = 0; n < 4; ++n)
      bfv[n] = *(const bf16x8*)(&Bs[(wc*64 + n*16 + rr)*104 + ks*32 + kq*8]);
    #pragma unroll
    for (int m = 0; m < 4; ++m)
      #pragma unroll
      for (int n = 0; n < 4; ++n)
        acc[m][n] = __builtin_amdgcn_mfma_f32_16x16x32_bf16(af[m], bfv[n], acc[m][n], 0, 0, 0);
  }
  const int cr = (lane >> 4) << 2, cc = lane & 15;
  __syncthreads();                         // all frag reads done -> reuse smem
  ushort* E = smem;                        // 128x136 ushorts (34.8KB <= 53KB)
  if (oy < 6) {
    // q/k: E[t][o] (pad 136), scatter 2B writes, coalesced row reads
    #pragma unroll
    for (int n = 0; n < 4; ++n) {
      const int ol = wc*64 + n*16 + cc;
      const float bias = (j == 0) ? b_attn[o0 + ol] : 0.f;
      #pragma unroll
      for (int m = 0; m < 4; ++m) {
        const int tb = wr*64 + m*16 + cr;
        #pragma unroll
        for (int r = 0; r < 4; ++r)
          E[(tb + r)*136 + ol] = f2bf(acc[m][n][r] + bias);
      }
    }
    __syncthreads();
    #pragma unroll
    for (int i = 0; i < 8; ++i) {
      int s = tid + 256*i;
      int tl = s >> 4, o8 = (s & 15)*8;
      ulonglong2 v = *(const ulonglong2*)(&E[tl*136 + o8]);
      int og = o0 + o8;
      int qkv = og / 384, rem = og % 384, head = rem / 48, c = rem % 48;
      ushort* dst = (qkv == 0 ? qf : kf) + ((size_t)head*TT + t0 + tl)*FF + fi*48 + c;
      *(ulonglong2*)dst = v;
    }
  } else {
    // v: E[o][t] (pad 136), packed 8B writes, coalesced t-row reads -> vT direct
    #pragma unroll
    for (int n = 0; n < 4; ++n) {
      const int ol = wc*64 + n*16 + cc;
      const float bias = (j == 0) ? b_attn[o0 + ol] : 0.f;
      #pragma unroll
      for (int m = 0; m < 4; ++m) {
        const int tb = wr*64 + m*16 + cr;
        uint2 pk;
        pk.x = (uint)f2bf(acc[m][n][0] + bias) | ((uint)f2bf(acc[m][n][1] + bias) << 16);
        pk.y = (uint)f2bf(acc[m][n][2] + bias) | ((uint)f2bf(acc[m][n][3] + bias) << 16);
        *(uint2*)(&E[ol*136 + tb]) = pk;
      }
    }
    __syncthreads();
    #pragma unroll
    for (int i = 0; i < 8; ++i) {
      int s = tid + 256*i;
      int ol = s >> 4, t8 = (s & 15)*8;
      ulonglong2 v = *(const ulonglong2*)(&E[ol*136 + t8]);
      int og = o0 + ol;
      int rem = og % 384, head = rem / 48, c = rem % 48;
      ushort* dst = vT + ((size_t)((head*16 + j)*48 + c))*TT + t0 + t8;
      *(ulonglong2*)dst = v;
    }
  }
}

// ---------------- K1c: qn/kn rank-1 features, one wave per token-head ----------------
__global__ __launch_bounds__(256) void k1c_extras(ushort* __restrict__ qf,
                                                  ushort* __restrict__ kf) {
  int th = blockIdx.x*4 + (threadIdx.x >> 6);
  int lane = threadIdx.x & 63;
  ushort* q = qf + (size_t)th*FF;
  ushort* k = kf + (size_t)th*FF;
  float qn = 0.f, kn = 0.f;
  if (lane < 36) {                       // elements 384..527 (sqrt2*proj planes)
    ushort4 a = *(const ushort4*)(q + 384 + lane*4);
    ushort4 b = *(const ushort4*)(k + 384 + lane*4);
    float x;
    x = bf2f(a.x); qn += x*x;  x = bf2f(a.y); qn += x*x;
    x = bf2f(a.z); qn += x*x;  x = bf2f(a.w); qn += x*x;
    x = bf2f(b.x); kn += x*x;  x = bf2f(b.y); kn += x*x;
    x = bf2f(b.z); kn += x*x;  x = bf2f(b.w); kn += x*x;
  }
  #pragma unroll
  for (int off = 32; off; off >>= 1) {
    qn += __shfl_xor(qn, off, 64);
    kn += __shfl_xor(kn, off, 64);
  }
  if (lane == 0) {                       // features hold sqrt(2)*proj -> *0.5
    q[528] = f2bf(qn*0.5f); q[529] = 0x3F80u;      // 1.0
    k[528] = 0xBF80u;       k[529] = f2bf(-kn*0.5f);
  }
  if (lane < 46) { q[530+lane] = 0; k[530+lane] = 0; }  // zero pad to FF=576
}

// ---------------- K2b: logits = (qf . kf)/sqrt(384), bf16 MFMA, BK=64 ----------------
__global__ __launch_bounds__(256) void k2b_logits_mfma(const ushort* __restrict__ qf,
                                                       const ushort* __restrict__ kf,
                                                       float* __restrict__ logits, int hh0) {
  const int lh = blockIdx.z, h = hh0 + lh;
  const int t0 = blockIdx.y*128, s0 = blockIdx.x*128;
  const ushort* Ag = qf + (size_t)h*TT*FF;
  const ushort* Bg = kf + (size_t)h*TT*FF;
  __shared__ __align__(16) ushort As[128*64];
  __shared__ __align__(16) ushort Bs[128*64];
  const int tid = threadIdx.x;
  const int lane = tid & 63, wid = tid >> 6;
  const int wr = wid >> 1, wc = wid & 1;
  const int rr = lane & 15, kq = lane >> 4;
  const int ar = tid >> 1, ac = (tid & 1)*4;      // staging row / 16B-chunk base
  f32x4 acc[4][4] = {};
  for (int kk = 0; kk < FF; kk += 64) {
    __syncthreads();
    {
      const ushort* ga = Ag + (size_t)(t0 + ar)*FF + kk;
      const ushort* gb = Bg + (size_t)(s0 + ar)*FF + kk;
      ulonglong2 av[4], bv[4];
      #pragma unroll
      for (int i = 0; i < 4; ++i) {
        av[i] = *(const ulonglong2*)(ga + (ac + i)*8);
        bv[i] = *(const ulonglong2*)(gb + (ac + i)*8);
      }
      #pragma unroll
      for (int i = 0; i < 4; ++i) {
        *(ulonglong2*)(&As[swz64(ar, ac + i)]) = av[i];
        *(ulonglong2*)(&Bs[swz64(ar, ac + i)]) = bv[i];
      }
    }
    __syncthreads();
    #pragma unroll
    for (int ks = 0; ks < 2; ++ks) {
      bf16x8 af[4], bfv[4];
      #pragma unroll
      for (int m = 0; m < 4; ++m) af[m]  = *(const bf16x8*)(&As[swz64(wr*64 + m*16 + rr, ks*4 + kq)]);
      #pragma unroll
      for (int n = 0; n < 4; ++n) bfv[n] = *(const bf16x8*)(&Bs[swz64(wc*64 + n*16 + rr, ks*4 + kq)]);
      #pragma unroll
      for (int m = 0; m < 4; ++m)
        #pragma unroll
        for (int n = 0; n < 4; ++n)
          acc[m][n] = __builtin_amdgcn_mfma_f32_16x16x32_bf16(af[m], bfv[n], acc[m][n], 0, 0, 0);
    }
  }
  const float iscl = 0.051031036307982884f;   // 1/sqrt(384)
  const int cr = (lane >> 4) << 2, cc = lane & 15;
  #pragma unroll
  for (int m = 0; m < 4; ++m)
    #pragma unroll
    for (int n = 0; n < 4; ++n) {
      size_t trow = (size_t)lh*TT + t0 + wr*64 + m*16 + cr;
      float* dst = logits + trow*TT + s0 + wc*64 + n*16 + cc;
      #pragma unroll
      for (int jj = 0; jj < 4; ++jj) dst[(size_t)jj*TT] = acc[m][n][jj]*iscl;
    }
}

// ---------------- K2c: row softmax, fp32 in -> bf16 probs out ----------------
__global__ __launch_bounds__(256) void k2c_softmax(const float* __restrict__ logits,
                                                   ushort* __restrict__ probs) {
  int row = blockIdx.x * 4 + (threadIdx.x >> 6);
  int lane = threadIdx.x & 63;
  const float* p = logits + (size_t)row * TT;
  ushort* pb = probs + (size_t)row * TT;
  float4 v[4];
  float mx = -1e30f;
  #pragma unroll
  for (int m = 0; m < 4; ++m) {
    v[m] = *(const float4*)(p + (m*64 + lane)*4);
    mx = fmaxf(mx, fmaxf(fmaxf(v[m].x, v[m].y), fmaxf(v[m].z, v[m].w)));
  }
  #pragma unroll
  for (int off = 32; off; off >>= 1) mx = fmaxf(mx, __shfl_xor(mx, off, 64));
  float sum = 0.f;
  #pragma unroll
  for (int m = 0; m < 4; ++m) {
    v[m].x = __expf(v[m].x - mx); v[m].y = __expf(v[m].y - mx);
    v[m].z = __expf(v[m].z - mx); v[m].w = __expf(v[m].w - mx);
    sum += v[m].x + v[m].y + v[m].z + v[m].w;
  }
  #pragma unroll
  for (int off = 32; off; off >>= 1) sum += __shfl_xor(sum, off, 64);
  float inv = 1.0f / sum;
  #pragma unroll
  for (int m = 0; m < 4; ++m) {
    ushort4 o;
    o.x = f2bf(v[m].x*inv); o.y = f2bf(v[m].y*inv);
    o.z = f2bf(v[m].z*inv); o.w = f2bf(v[m].w*inv);
    *(ushort4*)(pb + (m*64 + lane)*4) = o;
  }
}

// ---------------- K2d: aoP[j][t][h*48+c] = probs @ V, bf16 MFMA, BK=64 ----------------
__global__ __launch_bounds__(256) void k2d_pv_mfma(const ushort* __restrict__ probs,
                                                   const ushort* __restrict__ vT,
                                                   ushort* __restrict__ aoP, int hh0) {
  const int lh = blockIdx.z, h = hh0 + lh;
  const int t0 = blockIdx.y*128, c0 = blockIdx.x*64;
  const ushort* Ag = probs + (size_t)lh*TT*TT;
  const ushort* Bg = vT + (size_t)h*CK*TT;
  __shared__ __align__(16) ushort smem[128*64 + 64*64];   // As | Bs, reused as E
  ushort* As = smem;
  ushort* Bs = smem + 128*64;
  const int tid = threadIdx.x;
  const int lane = tid & 63, wid = tid >> 6;
  const int wr = wid >> 1, wc = wid & 1;
  const int rr = lane & 15, kq = lane >> 4;
  const int ar = tid >> 1, ac = (tid & 1)*4;
  const int br2 = tid >> 2, bc = (tid & 3)*2;
  f32x4 acc[4][2] = {};
  for (int kk = 0; kk < TT; kk += 64) {
    __syncthreads();
    {
      const ushort* ga = Ag + (size_t)(t0 + ar)*TT + kk;
      const ushort* gb = Bg + (size_t)(c0 + br2)*TT + kk;
      ulonglong2 av[4], bv[2];
      #pragma unroll
      for (int i = 0; i < 4; ++i) av[i] = *(const ulonglong2*)(ga + (ac + i)*8);
      #pragma unroll
      for (int i = 0; i < 2; ++i) bv[i] = *(const ulonglong2*)(gb + (bc + i)*8);
      #pragma unroll
      for (int i = 0; i < 4; ++i) *(ulonglong2*)(&As[swz64(ar, ac + i)]) = av[i];
      #pragma unroll
      for (int i = 0; i < 2; ++i) *(ulonglong2*)(&Bs[swz64(br2, bc + i)]) = bv[i];
    }
    __syncthreads();
    #pragma unroll
    for (int ks = 0; ks < 2; ++ks) {
      bf16x8 af[4], bfv[2];
      #pragma unroll
      for (int m = 0; m < 4; ++m) af[m]  = *(const bf16x8*)(&As[swz64(wr*64 + m*16 + rr, ks*4 + kq)]);
      #pragma unroll
      for (int n = 0; n < 2; ++n) bfv[n] = *(const bf16x8*)(&Bs[swz64(wc*32 + n*16 + rr, ks*4 + kq)]);
      #pragma unroll
      for (int m = 0; m < 4; ++m)
        #pragma unroll
        for (int n = 0; n < 2; ++n)
          acc[m][n] = __builtin_amdgcn_mfma_f32_16x16x32_bf16(af[m], bfv[n], acc[m][n], 0, 0, 0);
    }
  }
  const int cr = (lane >> 4) << 2, cc = lane & 15;
  __syncthreads();
  ushort* E = smem;                       // [128][72] (9216 <= 12288)
  #pragma unroll
  for (int m = 0; m < 4; ++m)
    #pragma unroll
    for (int n = 0; n < 2; ++n) {
      const int tb = wr*64 + m*16 + cr;
      const int cl = wc*32 + n*16 + cc;
      #pragma unroll
      for (int r = 0; r < 4; ++r)
        E[(tb + r)*72 + cl] = f2bf(acc[m][n][r]);
    }
  __syncthreads();
  #pragma unroll
  for (int i = 0; i < 4; ++i) {
    int s = tid + 256*i;
    int tl = s >> 3, c8 = (s & 7)*8;
    ulonglong2 v = *(const ulonglong2*)(&E[tl*72 + c8]);
    int cg = c0 + c8;
    int j = cg / 48, ch = cg % 48;
    *(ulonglong2*)(aoP + ((size_t)j*TT + t0 + tl)*384 + h*48 + ch) = v;
  }
}

// ---------------- K3: out-proj as 16 plane-GEMMs, bf16 MFMA + bias + residual ----------------
__global__ __launch_bounds__(256) void k3_mfma(const ushort* __restrict__ aoP,
                                               const ushort* __restrict__ wBt,
                                               const float* __restrict__ b_next,
                                               const float* __restrict__ hidden_b,
                                               float* __restrict__ out_b) {
  const int j = blockIdx.y, t0 = blockIdx.x*64;
  const int srcj = c_srcj[j];
  __shared__ __align__(16) ushort As[64*32];
  __shared__ __align__(16) ushort Bs[48*32];
  const int tid = threadIdx.x;
  const int lane = tid & 63, wid = tid >> 6;
  const int rr = lane & 15, kq = lane >> 4;
  const ushort* a0 = aoP + (size_t)j*TT*384;
  const ushort* a1 = aoP + (size_t)srcj*TT*384;
  const ushort* bw = wBt + (size_t)j*48*768;
  const int ar = tid >> 2, ac8 = (tid & 3);    // stage: 4 thr/row, 8 ushorts each
  f32x4 acc[3] = {};
  for (int kk = 0; kk < 768; kk += 32) {
    const ushort* srcA = (kk < 384) ? (a0 + kk) : (a1 + (kk - 384));
    __syncthreads();
    *(ulonglong2*)(&As[ar*32 + (((ac8 ^ (ar >> 2)) & 3) << 3)]) =
        *(const ulonglong2*)(srcA + (size_t)(t0 + ar)*384 + ac8*8);
    if (tid < 192)
      *(ulonglong2*)(&Bs[ar*32 + (((ac8 ^ (ar >> 2)) & 3) << 3)]) =
          *(const ulonglong2*)(bw + (size_t)ar*768 + kk + ac8*8);
    __syncthreads();
    bf16x8 af = *(const bf16x8*)(&As[(wid*16 + rr)*32 + (((kq ^ ((wid*16 + rr) >> 2)) & 3) << 3)]);
    #pragma unroll
    for (int n = 0; n < 3; ++n) {
      bf16x8 bf = *(const bf16x8*)(&Bs[(n*16 + rr)*32 + (((kq ^ ((n*16 + rr) >> 2)) & 3) << 3)]);
      acc[n] = __builtin_amdgcn_mfma_f32_16x16x32_bf16(af, bf, acc[n], 0, 0, 0);
    }
  }
  const int cr = (lane >> 4) << 2, cc = lane & 15;
  #pragma unroll
  for (int n = 0; n < 3; ++n) {
    int o = n*16 + cc;
    float bb = (j == 0) ? b_next[o] : 0.f;
    #pragma unroll
    for (int r = 0; r < 4; ++r) {
      int t = t0 + wid*16 + cr + r;
      size_t off = (size_t)t*768 + o*16 + j;
      out_b[off] = acc[n][r] + bb + hidden_b[off];
    }
  }
}

extern "C" void kernel_launch(void* const* d_in, const int* in_sizes, int n_in,
                              void* d_out, int out_size, void* d_ws, size_t ws_size,
                              hipStream_t stream) {
  const float* hidden = (const float*)d_in[0];
  const float* w_attn = (const float*)d_in[1];
  const float* b_attn = (const float*)d_in[2];
  const float* w_next = (const float*)d_in[3];
  const float* b_next = (const float*)d_in[4];
  const float* ln_w   = (const float*)d_in[5];
  float* out = (float*)d_out;
  float* ws = (float*)d_ws;

  // floats: qf+kf + vT + aoP + wBt + wB + hTb (all bf16 except logits)
  const size_t FIXED_FL = 4718592ull + 3145728ull + 3145728ull + 294912ull
                        + 884736ull + 393216ull;   // 12,582,912
  const size_t PER_HG   = 1048576ull + 524288ull;  // logits f32 + probs bf16 (in floats)
  int hg = 0;
  for (int g = 8; g >= 1; g >>= 1)
    if (ws_size >= (FIXED_FL + (size_t)g*PER_HG)*4) { hg = g; break; }
  if (hg == 0) {
    kfill<<<2048, 256, 0, stream>>>(out, (size_t)out_size, 1.0e6f);
    return;
  }

  float*  logits = ws;                                     // hg * 1M floats
  ushort* probs  = (ushort*)(ws + (size_t)hg*1048576);     // hg * 1M bf16
  ushort* qf     = (ushort*)(ws + (size_t)hg*PER_HG);      // 8192*576
  ushort* kf     = qf + (size_t)THD_B*FF;                  // 8192*576
  ushort* vT     = kf + (size_t)THD_B*FF;                  // 8*768*1024
  ushort* aoP    = vT + (size_t)THD_B*CK;                  // 16*1024*384
  ushort* wBt    = aoP + (size_t)16*TT*384;                // 16*48*768
  ushort* wB     = wBt + (size_t)16*48*768;                // 16*1152*96
  ushort* hTb    = wB + (size_t)16*1152*96;                // 16*1024*48

  k0b_wplanes<<<1152, 256, 0, stream>>>(w_next, wBt);
  k0c_wqkv<<<3456, 256, 0, stream>>>(w_attn, wB);
  for (int b = 0; b < BB; ++b) {
    const float* hid_b = hidden + (size_t)b*TT*768;
    float* out_b = out + (size_t)b*TT*768;
    k1_rmsnorm<<<TT, 256, 0, stream>>>(hid_b, ln_w, hTb);
    k1b_qkv_mfma<<<dim3(8, 9, 16), 256, 0, stream>>>(hTb, wB, b_attn, qf, kf, vT);
    k1c_extras<<<THD_B/4, 256, 0, stream>>>(qf, kf);
    for (int hh0 = 0; hh0 < HH; hh0 += hg) {
      k2b_logits_mfma<<<dim3(8, 8, hg), 256, 0, stream>>>(qf, kf, logits, hh0);
      k2c_softmax<<<hg*256, 256, 0, stream>>>(logits, probs);
      k2d_pv_mfma<<<dim3(12, 8, hg), 256, 0, stream>>>(probs, vT, aoP, hh0);
    }
    k3_mfma<<<dim3(16, 16), 256, 0, stream>>>(aoP, wBt, b_next, hid_b, out_b);
  }
}